// Round 1
// baseline (3811.921 us; speedup 1.0000x reference)
//
#include <hip/hip_runtime.h>

constexpr int H = 128;

// ---------------- GEMM: C[M,NCOL] = act(A[M,K] @ W[K,NCOL] (+bias)) --------
// 256 threads/block, BM rows/block. W fully staged in LDS; A tile staged
// (row-padded +4 floats to break bank conflicts). Per-thread TM x TN tile.
// TWOW: W = [W1 | W2] concatenated along columns (each K x NCOL/2).
template<int K, int NCOL, int BM, int TM, int TN, bool BIAS, bool RELU, bool TWOW>
__global__ __launch_bounds__(256)
void gemm_kernel(const float* __restrict__ A, const float* __restrict__ W1,
                 const float* __restrict__ W2, const float* __restrict__ bias,
                 float* __restrict__ C, int M)
{
    constexpr int CG = NCOL / TN;     // col groups
    constexpr int RG = 256 / CG;      // row groups
    static_assert(RG * TM == BM, "tile mismatch");
    __shared__ float Wlds[K][NCOL];
    __shared__ float Alds[BM][K + 4];

    const int tid  = threadIdx.x;
    const int row0 = blockIdx.x * BM;

    if constexpr (TWOW) {
        constexpr int HALF = NCOL / 2;
        constexpr int NL = K * HALF / (256 * 4);
        #pragma unroll
        for (int i = 0; i < NL; ++i) {
            int idx = (i * 256 + tid) * 4;
            int k = idx / HALF, c = idx % HALF;
            *(float4*)&Wlds[k][c]        = *(const float4*)&W1[idx];
            *(float4*)&Wlds[k][HALF + c] = *(const float4*)&W2[idx];
        }
    } else {
        constexpr int NL = K * NCOL / (256 * 4);
        #pragma unroll
        for (int i = 0; i < NL; ++i) {
            int idx = (i * 256 + tid) * 4;
            *(float4*)&Wlds[idx / NCOL][idx % NCOL] = *(const float4*)&W1[idx];
        }
    }
    {
        constexpr int NL = BM * K / (256 * 4);
        #pragma unroll
        for (int i = 0; i < NL; ++i) {
            int idx = (i * 256 + tid) * 4;
            int r = idx / K, c = idx % K;
            float4 v = make_float4(0.f, 0.f, 0.f, 0.f);
            if (row0 + r < M) v = *(const float4*)&A[(size_t)(row0 + r) * K + c];
            *(float4*)&Alds[r][c] = v;
        }
    }
    __syncthreads();

    const int cg = tid % CG, rg = tid / CG;
    const int c0 = cg * TN, r0 = rg * TM;

    float acc[TM][TN] = {};
    for (int k = 0; k < K; k += 4) {
        float4 a[TM];
        #pragma unroll
        for (int rr = 0; rr < TM; ++rr) a[rr] = *(const float4*)&Alds[r0 + rr][k];
        #pragma unroll
        for (int kk = 0; kk < 4; ++kk) {
            float w[TN];
            #pragma unroll
            for (int cc = 0; cc < TN; cc += 4) {
                float4 wv = *(const float4*)&Wlds[k + kk][c0 + cc];
                w[cc] = wv.x; w[cc + 1] = wv.y; w[cc + 2] = wv.z; w[cc + 3] = wv.w;
            }
            #pragma unroll
            for (int rr = 0; rr < TM; ++rr) {
                float av = (&a[rr].x)[kk];
                #pragma unroll
                for (int cc = 0; cc < TN; ++cc)
                    acc[rr][cc] = fmaf(av, w[cc], acc[rr][cc]);
            }
        }
    }

    #pragma unroll
    for (int rr = 0; rr < TM; ++rr) {
        int r = row0 + r0 + rr;
        if (r >= M) continue;
        #pragma unroll
        for (int cc = 0; cc < TN; cc += 4) {
            float o[4];
            #pragma unroll
            for (int j = 0; j < 4; ++j) {
                float v = acc[rr][cc + j];
                if constexpr (BIAS) v += bias[c0 + cc + j];
                if constexpr (RELU) v = fmaxf(v, 0.f);
                o[j] = v;
            }
            *(float4*)&C[(size_t)r * NCOL + c0 + cc] = make_float4(o[0], o[1], o[2], o[3]);
        }
    }
}

// ---------------- degree count / inverse ----------------
__global__ __launch_bounds__(256)
void count_kernel(const int* __restrict__ dst, int E, float* __restrict__ cnt)
{
    int i = blockIdx.x * 256 + threadIdx.x;
    if (i < E) unsafeAtomicAdd(&cnt[dst[i]], 1.0f);
}

__global__ __launch_bounds__(256)
void inv_kernel(float* __restrict__ c, int N)
{
    int i = blockIdx.x * 256 + threadIdx.x;
    if (i < N) c[i] = 1.0f / fmaxf(c[i], 1.0f);
}

// ---------------- edge scatter: Ydst[d][H + c] += Ysrc[s][c] * inv[d] ------
// 32 lanes per edge, float4 per lane (32*4 = 128 floats).
__global__ __launch_bounds__(256)
void scatter_kernel(const float* __restrict__ Ysrc, float* __restrict__ Ydst,
                    const int* __restrict__ esrc, const int* __restrict__ edst,
                    const float* __restrict__ inv, int E)
{
    int gid  = blockIdx.x * 256 + threadIdx.x;
    int eid  = gid >> 5;
    int lane = (gid & 31) * 4;
    if (eid >= E) return;
    int s = esrc[eid], d = edst[eid];
    float sc = inv[d];
    float4 v = *(const float4*)&Ysrc[(size_t)s * 2 * H + lane];
    float* out = &Ydst[(size_t)d * 2 * H + H + lane];
    unsafeAtomicAdd(out + 0, v.x * sc);
    unsafeAtomicAdd(out + 1, v.y * sc);
    unsafeAtomicAdd(out + 2, v.z * sc);
    unsafeAtomicAdd(out + 3, v.w * sc);
}

// ---------------- fused SAGE update: h = relu([BN]((h + Ypre + bl)*0.5)) ---
template<bool BN>
__global__ __launch_bounds__(256)
void update_kernel(float* __restrict__ h, const float* __restrict__ Y,
                   const float* __restrict__ bl, const float* __restrict__ gamma,
                   const float* __restrict__ beta, const float* __restrict__ mean,
                   const float* __restrict__ var, int N)
{
    int idx = blockIdx.x * 256 + threadIdx.x;
    int r = idx >> 5, c4 = (idx & 31) * 4;
    if (r >= N) return;
    float4 hv = *(const float4*)&h[(size_t)r * H + c4];
    float4 sv = *(const float4*)&Y[(size_t)r * 2 * H + H + c4];
    float o[4];
    #pragma unroll
    for (int j = 0; j < 4; ++j) {
        float u = ((&hv.x)[j] + (&sv.x)[j] + bl[c4 + j]) * 0.5f;
        if constexpr (BN)
            u = (u - mean[c4 + j]) * rsqrtf(var[c4 + j] + 1e-5f) * gamma[c4 + j] + beta[c4 + j];
        o[j] = fmaxf(u, 0.f);
    }
    *(float4*)&h[(size_t)r * H + c4] = make_float4(o[0], o[1], o[2], o[3]);
}

extern "C" void kernel_launch(void* const* d_in, const int* in_sizes, int n_in,
                              void* d_out, int out_size, void* d_ws, size_t ws_size,
                              hipStream_t stream)
{
    const float* x_u   = (const float*)d_in[0];
    const float* x_i   = (const float*)d_in[1];
    const int*   iu_src = (const int*)d_in[2];
    const int*   iu_dst = (const int*)d_in[3];
    const int*   ui_src = (const int*)d_in[4];
    const int*   ui_dst = (const int*)d_in[5];
    const float* Wp_u  = (const float*)d_in[6];
    const float* bp_u  = (const float*)d_in[7];
    const float* Wp_i  = (const float*)d_in[8];
    const float* bp_i  = (const float*)d_in[9];
    const float* Wl    = (const float*)d_in[10];
    const float* bl    = (const float*)d_in[11];
    const float* Wr    = (const float*)d_in[12];
    const float* gamma = (const float*)d_in[13];
    const float* beta  = (const float*)d_in[14];
    const float* mean  = (const float*)d_in[15];
    const float* var   = (const float*)d_in[16];
    const float* Wh    = (const float*)d_in[17];
    const float* bh    = (const float*)d_in[18];

    const int N_U = in_sizes[0] / 128;   // 50000
    const int N_I = in_sizes[1] / 64;    // 30000
    const int E   = in_sizes[2];         // 500000
    const int L   = in_sizes[10] / (H * H); // 2
    const int OUT = 32;

    // workspace layout (floats): ~30.8M floats = 123 MB
    float* ws   = (float*)d_ws;
    float* h_u  = ws;                              // [N_U, 128]
    float* h_i  = h_u + (size_t)N_U * H;           // [N_I, 128]
    float* Y_u  = h_i + (size_t)N_I * H;           // [N_U, 256]: [0:128)=h_u@Wl, [128:256)=h_u@Wr + scattered agg
    float* Y_i  = Y_u + (size_t)N_U * 2 * H;       // [N_I, 256]
    float* invU = Y_i + (size_t)N_I * 2 * H;       // [N_U]
    float* invI = invU + N_U;                      // [N_I]

    // degrees (same for both layers — edge lists are static)
    hipMemsetAsync(invU, 0, (size_t)(N_U + N_I) * sizeof(float), stream);
    count_kernel<<<(E + 255) / 256, 256, 0, stream>>>(iu_dst, E, invU);
    count_kernel<<<(E + 255) / 256, 256, 0, stream>>>(ui_dst, E, invI);
    inv_kernel<<<(N_U + N_I + 255) / 256, 256, 0, stream>>>(invU, N_U + N_I);

    // input projections (+bias, relu)
    gemm_kernel<128, 128, 64, 4, 8, true, true, false>
        <<<(N_U + 63) / 64, 256, 0, stream>>>(x_u, Wp_u, nullptr, bp_u, h_u, N_U);
    gemm_kernel<64, 128, 64, 4, 8, true, true, false>
        <<<(N_I + 63) / 64, 256, 0, stream>>>(x_i, Wp_i, nullptr, bp_i, h_i, N_I);

    for (int l = 0; l < L; ++l) {
        const float* Wl_l = Wl + (size_t)l * H * H;
        const float* Wr_l = Wr + (size_t)l * H * H;
        // Y = h @ [Wl | Wr]   (seg_mean(h)@Wl == seg_mean(h@Wl), by linearity)
        gemm_kernel<128, 256, 32, 4, 8, false, false, true>
            <<<(N_U + 31) / 32, 256, 0, stream>>>(h_u, Wl_l, Wr_l, nullptr, Y_u, N_U);
        gemm_kernel<128, 256, 32, 4, 8, false, false, true>
            <<<(N_I + 31) / 32, 256, 0, stream>>>(h_i, Wl_l, Wr_l, nullptr, Y_i, N_I);
        // scatter transformed neighbor feats (scaled by 1/deg) into pre-half
        scatter_kernel<<<(E * 32 + 255) / 256, 256, 0, stream>>>(Y_i, Y_u, iu_src, iu_dst, invU, E);
        scatter_kernel<<<(E * 32 + 255) / 256, 256, 0, stream>>>(Y_u, Y_i, ui_src, ui_dst, invI, E);
        // fused residual-mean + (BN) + relu
        update_kernel<true><<<((size_t)N_U * 32 + 255) / 256, 256, 0, stream>>>(
            h_u, Y_u, bl + l * H, gamma + l * H, beta + l * H, mean + l * H, var + l * H, N_U);
        update_kernel<false><<<((size_t)N_I * 32 + 255) / 256, 256, 0, stream>>>(
            h_i, Y_i, bl + l * H, nullptr, nullptr, nullptr, nullptr, N_I);
    }

    // head: out0 = h_u @ Wh + bh ; out1 = h_u
    float* out = (float*)d_out;
    gemm_kernel<128, 32, 128, 4, 4, true, false, false>
        <<<(N_U + 127) / 128, 256, 0, stream>>>(h_u, Wh, nullptr, bh, out, N_U);
    hipMemcpyAsync(out + (size_t)N_U * OUT, h_u, (size_t)N_U * H * sizeof(float),
                   hipMemcpyDeviceToDevice, stream);
}

// Round 2
// 765.997 us; speedup vs baseline: 4.9764x; 4.9764x over previous
//
#include <hip/hip_runtime.h>

constexpr int H = 128;

// ---------------- GEMM: C[M,NCOL] = act(A[M,K] @ W[K,NCOL] (+bias)) --------
template<int K, int NCOL, int BM, int TM, int TN, bool BIAS, bool RELU, bool TWOW>
__global__ __launch_bounds__(256)
void gemm_kernel(const float* __restrict__ A, const float* __restrict__ W1,
                 const float* __restrict__ W2, const float* __restrict__ bias,
                 float* __restrict__ C, int M)
{
    constexpr int CG = NCOL / TN;     // col groups
    constexpr int RG = 256 / CG;      // row groups
    static_assert(RG * TM == BM, "tile mismatch");
    __shared__ float Wlds[K][NCOL];
    __shared__ float Alds[BM][K + 4];

    const int tid  = threadIdx.x;
    const int row0 = blockIdx.x * BM;

    if constexpr (TWOW) {
        constexpr int HALF = NCOL / 2;
        constexpr int NL = K * HALF / (256 * 4);
        #pragma unroll
        for (int i = 0; i < NL; ++i) {
            int idx = (i * 256 + tid) * 4;
            int k = idx / HALF, c = idx % HALF;
            *(float4*)&Wlds[k][c]        = *(const float4*)&W1[idx];
            *(float4*)&Wlds[k][HALF + c] = *(const float4*)&W2[idx];
        }
    } else {
        constexpr int NL = K * NCOL / (256 * 4);
        #pragma unroll
        for (int i = 0; i < NL; ++i) {
            int idx = (i * 256 + tid) * 4;
            *(float4*)&Wlds[idx / NCOL][idx % NCOL] = *(const float4*)&W1[idx];
        }
    }
    {
        constexpr int NL = BM * K / (256 * 4);
        #pragma unroll
        for (int i = 0; i < NL; ++i) {
            int idx = (i * 256 + tid) * 4;
            int r = idx / K, c = idx % K;
            float4 v = make_float4(0.f, 0.f, 0.f, 0.f);
            if (row0 + r < M) v = *(const float4*)&A[(size_t)(row0 + r) * K + c];
            *(float4*)&Alds[r][c] = v;
        }
    }
    __syncthreads();

    const int cg = tid % CG, rg = tid / CG;
    const int c0 = cg * TN, r0 = rg * TM;

    float acc[TM][TN] = {};
    for (int k = 0; k < K; k += 4) {
        float4 a[TM];
        #pragma unroll
        for (int rr = 0; rr < TM; ++rr) a[rr] = *(const float4*)&Alds[r0 + rr][k];
        #pragma unroll
        for (int kk = 0; kk < 4; ++kk) {
            float w[TN];
            #pragma unroll
            for (int cc = 0; cc < TN; cc += 4) {
                float4 wv = *(const float4*)&Wlds[k + kk][c0 + cc];
                w[cc] = wv.x; w[cc + 1] = wv.y; w[cc + 2] = wv.z; w[cc + 3] = wv.w;
            }
            #pragma unroll
            for (int rr = 0; rr < TM; ++rr) {
                float av = (&a[rr].x)[kk];
                #pragma unroll
                for (int cc = 0; cc < TN; ++cc)
                    acc[rr][cc] = fmaf(av, w[cc], acc[rr][cc]);
            }
        }
    }

    #pragma unroll
    for (int rr = 0; rr < TM; ++rr) {
        int r = row0 + r0 + rr;
        if (r >= M) continue;
        #pragma unroll
        for (int cc = 0; cc < TN; cc += 4) {
            float o[4];
            #pragma unroll
            for (int j = 0; j < 4; ++j) {
                float v = acc[rr][cc + j];
                if constexpr (BIAS) v += bias[c0 + cc + j];
                if constexpr (RELU) v = fmaxf(v, 0.f);
                o[j] = v;
            }
            *(float4*)&C[(size_t)r * NCOL + c0 + cc] = make_float4(o[0], o[1], o[2], o[3]);
        }
    }
}

// ---------------- CSR build: degree count, scan, fill ----------------
__global__ __launch_bounds__(256)
void count_kernel(const int* __restrict__ dst, int E, int* __restrict__ deg)
{
    int i = blockIdx.x * 256 + threadIdx.x;
    if (i < E) atomicAdd(&deg[dst[i]], 1);
}

// single-block exclusive scan of deg[0:N] -> rowptr[0:N+1] and cursor copy
__global__ __launch_bounds__(1024)
void scan_kernel(const int* __restrict__ deg, int N,
                 int* __restrict__ rowptr, int* __restrict__ cursor)
{
    __shared__ int buf[1024];
    __shared__ int carry;
    const int t = threadIdx.x;
    if (t == 0) carry = 0;
    __syncthreads();
    for (int base = 0; base < N; base += 1024) {
        int v = (base + t < N) ? deg[base + t] : 0;
        buf[t] = v;
        __syncthreads();
        #pragma unroll
        for (int off = 1; off < 1024; off <<= 1) {
            int x = (t >= off) ? buf[t - off] : 0;
            __syncthreads();
            buf[t] += x;
            __syncthreads();
        }
        int incl = buf[t];
        int excl = incl - v + carry;
        if (base + t < N) { rowptr[base + t] = excl; cursor[base + t] = excl; }
        __syncthreads();
        if (t == 1023) carry += incl;
        __syncthreads();
    }
    if (t == 0) rowptr[N] = carry;
}

__global__ __launch_bounds__(256)
void fill_kernel(const int* __restrict__ src, const int* __restrict__ dst, int E,
                 int* __restrict__ cursor, int* __restrict__ lists)
{
    int i = blockIdx.x * 256 + threadIdx.x;
    if (i >= E) return;
    int d = dst[i];
    int pos = atomicAdd(&cursor[d], 1);
    lists[pos] = src[i];
}

// ---------------- fused gather + SAGE update ----------------
// One 64-lane wave per dst node; lane owns 2 consecutive floats (float2).
// h[d] = relu([BN]( (h[d] + mean_{s in N(d)} Ysrc[s][0:128] + Ydst[d][128:256] + bl) * 0.5 ))
template<bool BN>
__global__ __launch_bounds__(256)
void gather_update_kernel(const float* __restrict__ Ysrc, const float* __restrict__ Ydst,
                          float* __restrict__ h,
                          const int* __restrict__ rowptr, const int* __restrict__ lists,
                          const float* __restrict__ bl, const float* __restrict__ gamma,
                          const float* __restrict__ beta, const float* __restrict__ mean,
                          const float* __restrict__ var, int N)
{
    const int node = blockIdx.x * 4 + (threadIdx.x >> 6);
    const int c2   = (threadIdx.x & 63) * 2;
    if (node >= N) return;
    const int beg = rowptr[node], end = rowptr[node + 1];

    float ax0 = 0.f, ay0 = 0.f, ax1 = 0.f, ay1 = 0.f;
    int e = beg;
    for (; e + 1 < end; e += 2) {
        int s0 = lists[e], s1 = lists[e + 1];
        float2 v0 = *(const float2*)&Ysrc[(size_t)s0 * 2 * H + c2];
        float2 v1 = *(const float2*)&Ysrc[(size_t)s1 * 2 * H + c2];
        ax0 += v0.x; ay0 += v0.y;
        ax1 += v1.x; ay1 += v1.y;
    }
    if (e < end) {
        int s0 = lists[e];
        float2 v0 = *(const float2*)&Ysrc[(size_t)s0 * 2 * H + c2];
        ax0 += v0.x; ay0 += v0.y;
    }
    ax0 += ax1; ay0 += ay1;
    const float sc = (end > beg) ? 1.0f / (float)(end - beg) : 0.f;

    float2 yv = *(const float2*)&Ydst[(size_t)node * 2 * H + H + c2];
    float2 hv = *(const float2*)&h[(size_t)node * H + c2];

    float u0 = (hv.x + ax0 * sc + yv.x + bl[c2])     * 0.5f;
    float u1 = (hv.y + ay0 * sc + yv.y + bl[c2 + 1]) * 0.5f;
    if constexpr (BN) {
        u0 = (u0 - mean[c2])     * rsqrtf(var[c2]     + 1e-5f) * gamma[c2]     + beta[c2];
        u1 = (u1 - mean[c2 + 1]) * rsqrtf(var[c2 + 1] + 1e-5f) * gamma[c2 + 1] + beta[c2 + 1];
    }
    float2 o = make_float2(fmaxf(u0, 0.f), fmaxf(u1, 0.f));
    *(float2*)&h[(size_t)node * H + c2] = o;
}

extern "C" void kernel_launch(void* const* d_in, const int* in_sizes, int n_in,
                              void* d_out, int out_size, void* d_ws, size_t ws_size,
                              hipStream_t stream)
{
    const float* x_u   = (const float*)d_in[0];
    const float* x_i   = (const float*)d_in[1];
    const int*   iu_src = (const int*)d_in[2];
    const int*   iu_dst = (const int*)d_in[3];
    const int*   ui_src = (const int*)d_in[4];
    const int*   ui_dst = (const int*)d_in[5];
    const float* Wp_u  = (const float*)d_in[6];
    const float* bp_u  = (const float*)d_in[7];
    const float* Wp_i  = (const float*)d_in[8];
    const float* bp_i  = (const float*)d_in[9];
    const float* Wl    = (const float*)d_in[10];
    const float* bl    = (const float*)d_in[11];
    const float* Wr    = (const float*)d_in[12];
    const float* gamma = (const float*)d_in[13];
    const float* beta  = (const float*)d_in[14];
    const float* mean  = (const float*)d_in[15];
    const float* var   = (const float*)d_in[16];
    const float* Wh    = (const float*)d_in[17];
    const float* bh    = (const float*)d_in[18];

    const int N_U = in_sizes[0] / 128;      // 50000
    const int N_I = in_sizes[1] / 64;       // 30000
    const int E   = in_sizes[2];            // 500000
    const int L   = in_sizes[10] / (H * H); // 2
    const int OUT = 32;

    float* out = (float*)d_out;
    // h_u lives in its final output slot (fully rewritten every launch)
    float* h_u = out + (size_t)N_U * OUT;

    // workspace layout
    float* ws   = (float*)d_ws;
    float* h_i  = ws;                               // [N_I, 128]
    float* Y_u  = h_i + (size_t)N_I * H;            // [N_U, 256]
    float* Y_i  = Y_u + (size_t)N_U * 2 * H;        // [N_I, 256]
    int*   ip   = (int*)(Y_i + (size_t)N_I * 2 * H);
    int* degU    = ip;               ip += N_U;
    int* degI    = ip;               ip += N_I;
    int* rowU    = ip;               ip += N_U + 1;
    int* rowI    = ip;               ip += N_I + 1;
    int* curU    = ip;               ip += N_U;
    int* curI    = ip;               ip += N_I;
    int* listsU  = ip;               ip += E;       // src per CSR slot (dst=user)
    int* listsI  = ip;               ip += E;       // src per CSR slot (dst=item)

    // ---- CSR build (edge lists static across layers) ----
    hipMemsetAsync(degU, 0, (size_t)(N_U + N_I) * sizeof(int), stream);
    count_kernel<<<(E + 255) / 256, 256, 0, stream>>>(iu_dst, E, degU);
    count_kernel<<<(E + 255) / 256, 256, 0, stream>>>(ui_dst, E, degI);
    scan_kernel<<<1, 1024, 0, stream>>>(degU, N_U, rowU, curU);
    scan_kernel<<<1, 1024, 0, stream>>>(degI, N_I, rowI, curI);
    fill_kernel<<<(E + 255) / 256, 256, 0, stream>>>(iu_src, iu_dst, E, curU, listsU);
    fill_kernel<<<(E + 255) / 256, 256, 0, stream>>>(ui_src, ui_dst, E, curI, listsI);

    // ---- input projections (+bias, relu) ----
    gemm_kernel<128, 128, 64, 4, 8, true, true, false>
        <<<(N_U + 63) / 64, 256, 0, stream>>>(x_u, Wp_u, nullptr, bp_u, h_u, N_U);
    gemm_kernel<64, 128, 64, 4, 8, true, true, false>
        <<<(N_I + 63) / 64, 256, 0, stream>>>(x_i, Wp_i, nullptr, bp_i, h_i, N_I);

    for (int l = 0; l < L; ++l) {
        const float* Wl_l = Wl + (size_t)l * H * H;
        const float* Wr_l = Wr + (size_t)l * H * H;
        // Y = h @ [Wl | Wr]   (seg_mean(h)@Wl == seg_mean(h@Wl), by linearity)
        gemm_kernel<128, 256, 32, 4, 8, false, false, true>
            <<<(N_U + 31) / 32, 256, 0, stream>>>(h_u, Wl_l, Wr_l, nullptr, Y_u, N_U);
        gemm_kernel<128, 256, 32, 4, 8, false, false, true>
            <<<(N_I + 31) / 32, 256, 0, stream>>>(h_i, Wl_l, Wr_l, nullptr, Y_i, N_I);
        // fused gather-mean + residual + BN + relu (reads only OLD-h-derived Y)
        gather_update_kernel<true><<<(N_U + 3) / 4, 256, 0, stream>>>(
            Y_i, Y_u, h_u, rowU, listsU,
            bl + l * H, gamma + l * H, beta + l * H, mean + l * H, var + l * H, N_U);
        gather_update_kernel<false><<<(N_I + 3) / 4, 256, 0, stream>>>(
            Y_u, Y_i, h_i, rowI, listsI,
            bl + l * H, nullptr, nullptr, nullptr, nullptr, N_I);
    }

    // ---- head: out0 = h_u @ Wh + bh (h_u already in place as out1) ----
    gemm_kernel<128, 32, 128, 4, 4, true, false, false>
        <<<(N_U + 127) / 128, 256, 0, stream>>>(h_u, Wh, nullptr, bh, out, N_U);
}

// Round 3
// 632.332 us; speedup vs baseline: 6.0284x; 1.2114x over previous
//
#include <hip/hip_runtime.h>

constexpr int H = 128;

// ---------------- GEMM: C[M,NCOL] = act(A[M,K] @ W[K,NCOL] (+bias)) --------
template<int K, int NCOL, int BM, int TM, int TN, bool BIAS, bool RELU, bool TWOW>
__global__ __launch_bounds__(256)
void gemm_kernel(const float* __restrict__ A, const float* __restrict__ W1,
                 const float* __restrict__ W2, const float* __restrict__ bias,
                 float* __restrict__ C, int M)
{
    constexpr int CG = NCOL / TN;     // col groups
    constexpr int RG = 256 / CG;      // row groups
    static_assert(RG * TM == BM, "tile mismatch");
    __shared__ float Wlds[K][NCOL];
    __shared__ float Alds[BM][K + 4];

    const int tid  = threadIdx.x;
    const int row0 = blockIdx.x * BM;

    if constexpr (TWOW) {
        constexpr int HALF = NCOL / 2;
        constexpr int NL = K * HALF / (256 * 4);
        #pragma unroll
        for (int i = 0; i < NL; ++i) {
            int idx = (i * 256 + tid) * 4;
            int k = idx / HALF, c = idx % HALF;
            *(float4*)&Wlds[k][c]        = *(const float4*)&W1[idx];
            *(float4*)&Wlds[k][HALF + c] = *(const float4*)&W2[idx];
        }
    } else {
        constexpr int NL = K * NCOL / (256 * 4);
        #pragma unroll
        for (int i = 0; i < NL; ++i) {
            int idx = (i * 256 + tid) * 4;
            *(float4*)&Wlds[idx / NCOL][idx % NCOL] = *(const float4*)&W1[idx];
        }
    }
    {
        constexpr int NL = BM * K / (256 * 4);
        #pragma unroll
        for (int i = 0; i < NL; ++i) {
            int idx = (i * 256 + tid) * 4;
            int r = idx / K, c = idx % K;
            float4 v = make_float4(0.f, 0.f, 0.f, 0.f);
            if (row0 + r < M) v = *(const float4*)&A[(size_t)(row0 + r) * K + c];
            *(float4*)&Alds[r][c] = v;
        }
    }
    __syncthreads();

    const int cg = tid % CG, rg = tid / CG;
    const int c0 = cg * TN, r0 = rg * TM;

    float acc[TM][TN] = {};
    for (int k = 0; k < K; k += 4) {
        float4 a[TM];
        #pragma unroll
        for (int rr = 0; rr < TM; ++rr) a[rr] = *(const float4*)&Alds[r0 + rr][k];
        #pragma unroll
        for (int kk = 0; kk < 4; ++kk) {
            float w[TN];
            #pragma unroll
            for (int cc = 0; cc < TN; cc += 4) {
                float4 wv = *(const float4*)&Wlds[k + kk][c0 + cc];
                w[cc] = wv.x; w[cc + 1] = wv.y; w[cc + 2] = wv.z; w[cc + 3] = wv.w;
            }
            #pragma unroll
            for (int rr = 0; rr < TM; ++rr) {
                float av = (&a[rr].x)[kk];
                #pragma unroll
                for (int cc = 0; cc < TN; ++cc)
                    acc[rr][cc] = fmaf(av, w[cc], acc[rr][cc]);
            }
        }
    }

    #pragma unroll
    for (int rr = 0; rr < TM; ++rr) {
        int r = row0 + r0 + rr;
        if (r >= M) continue;
        #pragma unroll
        for (int cc = 0; cc < TN; cc += 4) {
            float o[4];
            #pragma unroll
            for (int j = 0; j < 4; ++j) {
                float v = acc[rr][cc + j];
                if constexpr (BIAS) v += bias[c0 + cc + j];
                if constexpr (RELU) v = fmaxf(v, 0.f);
                o[j] = v;
            }
            *(float4*)&C[(size_t)r * NCOL + c0 + cc] = make_float4(o[0], o[1], o[2], o[3]);
        }
    }
}

// ---------------- CSR build ----------------
__global__ __launch_bounds__(256)
void count_kernel(const int* __restrict__ dst, int E, int* __restrict__ deg)
{
    int i = blockIdx.x * 256 + threadIdx.x;
    if (i < E) atomicAdd(&deg[dst[i]], 1);
}

// Phase A: per-block (1024 elems) exclusive scan + block totals
__global__ __launch_bounds__(256)
void scan_a_kernel(const int* __restrict__ deg, int N,
                   int* __restrict__ locEx, int* __restrict__ blockSums)
{
    __shared__ int buf[256];
    const int t = threadIdx.x;
    const int base = blockIdx.x * 1024 + t * 4;
    int v[4];
    #pragma unroll
    for (int j = 0; j < 4; ++j) v[j] = (base + j < N) ? deg[base + j] : 0;
    const int s = v[0] + v[1] + v[2] + v[3];
    buf[t] = s;
    __syncthreads();
    #pragma unroll
    for (int off = 1; off < 256; off <<= 1) {
        int x = (t >= off) ? buf[t - off] : 0;
        __syncthreads();
        buf[t] += x;
        __syncthreads();
    }
    int run = buf[t] - s;   // exclusive
    if (t == 255) blockSums[blockIdx.x] = buf[255];
    #pragma unroll
    for (int j = 0; j < 4; ++j) {
        if (base + j < N) locEx[base + j] = run;
        run += v[j];
    }
}

// Phase B: exclusive-scan the block sums in-place (nb small); total -> *totalOut
__global__ __launch_bounds__(64)
void scan_b_kernel(int* __restrict__ bsum, int nb, int* __restrict__ totalOut)
{
    const int t = threadIdx.x;
    if (nb <= 64) {
        int v = (t < nb) ? bsum[t] : 0;
        int incl = v;
        #pragma unroll
        for (int off = 1; off < 64; off <<= 1) {
            int x = __shfl_up(incl, off, 64);
            if (t >= off) incl += x;
        }
        if (t < nb) bsum[t] = incl - v;
        if (t == 63) *totalOut = incl;
    } else if (t == 0) {
        int run = 0;
        for (int i = 0; i < nb; ++i) { int v = bsum[i]; bsum[i] = run; run += v; }
        *totalOut = run;
    }
}

// Phase C: add block offsets, write rowptr + cursor
__global__ __launch_bounds__(256)
void scan_c_kernel(const int* __restrict__ locEx, const int* __restrict__ bsum, int N,
                   int* __restrict__ rowptr, int* __restrict__ cursor)
{
    int i = blockIdx.x * 256 + threadIdx.x;
    if (i < N) {
        int v = locEx[i] + bsum[i >> 10];
        rowptr[i] = v;
        cursor[i] = v;
    }
}

__global__ __launch_bounds__(256)
void fill_kernel(const int* __restrict__ src, const int* __restrict__ dst, int E,
                 int* __restrict__ cursor, int* __restrict__ lists)
{
    int i = blockIdx.x * 256 + threadIdx.x;
    if (i >= E) return;
    int d = dst[i];
    int pos = atomicAdd(&cursor[d], 1);
    lists[pos] = src[i];
}

// ---------------- fused gather + SAGE update ----------------
// One 64-lane wave per dst node; lane owns 2 consecutive floats (float2).
template<bool BN>
__global__ __launch_bounds__(256)
void gather_update_kernel(const float* __restrict__ Ysrc, const float* __restrict__ Ydst,
                          float* __restrict__ h,
                          const int* __restrict__ rowptr, const int* __restrict__ lists,
                          const float* __restrict__ bl, const float* __restrict__ gamma,
                          const float* __restrict__ beta, const float* __restrict__ mean,
                          const float* __restrict__ var, int N)
{
    const int node = blockIdx.x * 4 + (threadIdx.x >> 6);
    const int c2   = (threadIdx.x & 63) * 2;
    if (node >= N) return;
    const int beg = rowptr[node], end = rowptr[node + 1];

    float ax0 = 0.f, ay0 = 0.f, ax1 = 0.f, ay1 = 0.f;
    int e = beg;
    for (; e + 1 < end; e += 2) {
        int s0 = lists[e], s1 = lists[e + 1];
        float2 v0 = *(const float2*)&Ysrc[(size_t)s0 * 2 * H + c2];
        float2 v1 = *(const float2*)&Ysrc[(size_t)s1 * 2 * H + c2];
        ax0 += v0.x; ay0 += v0.y;
        ax1 += v1.x; ay1 += v1.y;
    }
    if (e < end) {
        int s0 = lists[e];
        float2 v0 = *(const float2*)&Ysrc[(size_t)s0 * 2 * H + c2];
        ax0 += v0.x; ay0 += v0.y;
    }
    ax0 += ax1; ay0 += ay1;
    const float sc = (end > beg) ? 1.0f / (float)(end - beg) : 0.f;

    float2 yv = *(const float2*)&Ydst[(size_t)node * 2 * H + H + c2];
    float2 hv = *(const float2*)&h[(size_t)node * H + c2];

    float u0 = (hv.x + ax0 * sc + yv.x + bl[c2])     * 0.5f;
    float u1 = (hv.y + ay0 * sc + yv.y + bl[c2 + 1]) * 0.5f;
    if constexpr (BN) {
        u0 = (u0 - mean[c2])     * rsqrtf(var[c2]     + 1e-5f) * gamma[c2]     + beta[c2];
        u1 = (u1 - mean[c2 + 1]) * rsqrtf(var[c2 + 1] + 1e-5f) * gamma[c2 + 1] + beta[c2 + 1];
    }
    float2 o = make_float2(fmaxf(u0, 0.f), fmaxf(u1, 0.f));
    *(float2*)&h[(size_t)node * H + c2] = o;
}

extern "C" void kernel_launch(void* const* d_in, const int* in_sizes, int n_in,
                              void* d_out, int out_size, void* d_ws, size_t ws_size,
                              hipStream_t stream)
{
    const float* x_u   = (const float*)d_in[0];
    const float* x_i   = (const float*)d_in[1];
    const int*   iu_src = (const int*)d_in[2];
    const int*   iu_dst = (const int*)d_in[3];
    const int*   ui_src = (const int*)d_in[4];
    const int*   ui_dst = (const int*)d_in[5];
    const float* Wp_u  = (const float*)d_in[6];
    const float* bp_u  = (const float*)d_in[7];
    const float* Wp_i  = (const float*)d_in[8];
    const float* bp_i  = (const float*)d_in[9];
    const float* Wl    = (const float*)d_in[10];
    const float* bl    = (const float*)d_in[11];
    const float* Wr    = (const float*)d_in[12];
    const float* gamma = (const float*)d_in[13];
    const float* beta  = (const float*)d_in[14];
    const float* mean  = (const float*)d_in[15];
    const float* var   = (const float*)d_in[16];
    const float* Wh    = (const float*)d_in[17];
    const float* bh    = (const float*)d_in[18];

    const int N_U = in_sizes[0] / 128;      // 50000
    const int N_I = in_sizes[1] / 64;       // 30000
    const int E   = in_sizes[2];            // 500000
    const int L   = in_sizes[10] / (H * H); // 2
    const int OUT = 32;

    float* out = (float*)d_out;
    float* h_u = out + (size_t)N_U * OUT;   // h_u lives in its output slot

    // workspace layout
    float* ws   = (float*)d_ws;
    float* h_i  = ws;                               // [N_I, 128]
    float* Y_u  = h_i + (size_t)N_I * H;            // [N_U, 256]
    float* Y_i  = Y_u + (size_t)N_U * 2 * H;        // [N_I, 256]
    int*   ip   = (int*)(Y_i + (size_t)N_I * 2 * H);
    int* degU    = ip;               ip += N_U;
    int* degI    = ip;               ip += N_I;
    int* rowU    = ip;               ip += N_U + 1;
    int* rowI    = ip;               ip += N_I + 1;
    int* curU    = ip;               ip += N_U;
    int* curI    = ip;               ip += N_I;
    int* listsU  = ip;               ip += E;
    int* listsI  = ip;               ip += E;
    int* locEx   = ip;               ip += (N_U > N_I ? N_U : N_I);
    int* bsum    = ip;               ip += 128;

    const int nbU = (N_U + 1023) / 1024;
    const int nbI = (N_I + 1023) / 1024;

    // ---- CSR build ----
    hipMemsetAsync(degU, 0, (size_t)(N_U + N_I) * sizeof(int), stream);
    count_kernel<<<(E + 255) / 256, 256, 0, stream>>>(iu_dst, E, degU);
    count_kernel<<<(E + 255) / 256, 256, 0, stream>>>(ui_dst, E, degI);

    scan_a_kernel<<<nbU, 256, 0, stream>>>(degU, N_U, locEx, bsum);
    scan_b_kernel<<<1, 64, 0, stream>>>(bsum, nbU, rowU + N_U);
    scan_c_kernel<<<(N_U + 255) / 256, 256, 0, stream>>>(locEx, bsum, N_U, rowU, curU);
    fill_kernel<<<(E + 255) / 256, 256, 0, stream>>>(iu_src, iu_dst, E, curU, listsU);

    scan_a_kernel<<<nbI, 256, 0, stream>>>(degI, N_I, locEx, bsum);
    scan_b_kernel<<<1, 64, 0, stream>>>(bsum, nbI, rowI + N_I);
    scan_c_kernel<<<(N_I + 255) / 256, 256, 0, stream>>>(locEx, bsum, N_I, rowI, curI);
    fill_kernel<<<(E + 255) / 256, 256, 0, stream>>>(ui_src, ui_dst, E, curI, listsI);

    // ---- input projections (+bias, relu) ----
    gemm_kernel<128, 128, 64, 4, 8, true, true, false>
        <<<(N_U + 63) / 64, 256, 0, stream>>>(x_u, Wp_u, nullptr, bp_u, h_u, N_U);
    gemm_kernel<64, 128, 64, 4, 8, true, true, false>
        <<<(N_I + 63) / 64, 256, 0, stream>>>(x_i, Wp_i, nullptr, bp_i, h_i, N_I);

    for (int l = 0; l < L; ++l) {
        const float* Wl_l = Wl + (size_t)l * H * H;
        const float* Wr_l = Wr + (size_t)l * H * H;
        gemm_kernel<128, 256, 32, 4, 8, false, false, true>
            <<<(N_U + 31) / 32, 256, 0, stream>>>(h_u, Wl_l, Wr_l, nullptr, Y_u, N_U);
        gemm_kernel<128, 256, 32, 4, 8, false, false, true>
            <<<(N_I + 31) / 32, 256, 0, stream>>>(h_i, Wl_l, Wr_l, nullptr, Y_i, N_I);
        gather_update_kernel<true><<<(N_U + 3) / 4, 256, 0, stream>>>(
            Y_i, Y_u, h_u, rowU, listsU,
            bl + l * H, gamma + l * H, beta + l * H, mean + l * H, var + l * H, N_U);
        gather_update_kernel<false><<<(N_I + 3) / 4, 256, 0, stream>>>(
            Y_u, Y_i, h_i, rowI, listsI,
            bl + l * H, nullptr, nullptr, nullptr, nullptr, N_I);
    }

    // ---- head: out0 = h_u @ Wh + bh (h_u already in place as out1) ----
    gemm_kernel<128, 32, 128, 4, 4, true, false, false>
        <<<(N_U + 127) / 128, 256, 0, stream>>>(h_u, Wh, nullptr, bh, out, N_U);
}

// Round 4
// 428.188 us; speedup vs baseline: 8.9024x; 1.4768x over previous
//
#include <hip/hip_runtime.h>

constexpr int H = 128;

typedef short bf16x8 __attribute__((ext_vector_type(8)));
typedef float f32x4  __attribute__((ext_vector_type(4)));

__device__ __forceinline__ ushort f2b(float f) {
    uint u = __float_as_uint(f);
    u += 0x7fff + ((u >> 16) & 1);      // round-to-nearest-even
    return (ushort)(u >> 16);
}

// ---------------- W pack: frag[s][t0+t][lane][j] = W[s*32 + 8*(l/16) + j][t*16 + l%16]
__global__ __launch_bounds__(256)
void pack_w_kernel(const float* __restrict__ W, int ldw, int S, int t0, int nct,
                   int nctTot, ushort* __restrict__ dst)
{
    int f = blockIdx.x * 256 + threadIdx.x;
    int total = S * nct * 64;
    if (f >= total) return;
    int l = f & 63;
    int t = (f >> 6) % nct;
    int s = (f >> 6) / nct;
    int col = t * 16 + (l & 15);
    int kb  = s * 32 + (l >> 4) * 8;
    ushort o[8];
    #pragma unroll
    for (int j = 0; j < 8; ++j) o[j] = f2b(W[(size_t)(kb + j) * ldw + col]);
    ushort* d = dst + ((size_t)(s * nctTot + t0 + t) * 64 + l) * 8;
    *(uint4*)d = *(uint4*)o;
}

// ---------------- MFMA GEMM: C[M, NCT*16] = act(A[M,K] @ Wpack (+bias)) ------
// 256 threads = 4 waves; wave w computes rows [blk*64 + 16w, +16) x all NCT*16 cols.
// A fp32 row-major, converted inline to bf16. Wpack in fragment order.
template<int K, int NCT, bool BIAS, bool RELU>
__global__ __launch_bounds__(256)
void mfma_gemm_kernel(const float* __restrict__ A, const ushort* __restrict__ Wp,
                      const float* __restrict__ bias, float* __restrict__ C, int M)
{
    constexpr int S   = K / 32;
    constexpr int LDC = NCT * 16;
    const int wave = threadIdx.x >> 6;
    const int lane = threadIdx.x & 63;
    const int row0 = blockIdx.x * 64 + wave * 16;

    int ar = row0 + (lane & 15);
    if (ar >= M) ar = M - 1;                      // clamp loads; stores guarded
    const float* arow = A + (size_t)ar * K + (lane >> 4) * 8;
    const bf16x8* W8  = (const bf16x8*)Wp;

    f32x4 acc[NCT];
    #pragma unroll
    for (int t = 0; t < NCT; ++t) acc[t] = (f32x4){0.f, 0.f, 0.f, 0.f};

    #pragma unroll
    for (int s = 0; s < S; ++s) {
        float4 f0 = *(const float4*)(arow + s * 32);
        float4 f1 = *(const float4*)(arow + s * 32 + 4);
        bf16x8 a;
        a[0] = (short)f2b(f0.x); a[1] = (short)f2b(f0.y);
        a[2] = (short)f2b(f0.z); a[3] = (short)f2b(f0.w);
        a[4] = (short)f2b(f1.x); a[5] = (short)f2b(f1.y);
        a[6] = (short)f2b(f1.z); a[7] = (short)f2b(f1.w);
        #pragma unroll
        for (int t = 0; t < NCT; ++t) {
            bf16x8 b = W8[(size_t)(s * NCT + t) * 64 + lane];
            acc[t] = __builtin_amdgcn_mfma_f32_16x16x32_bf16(a, b, acc[t], 0, 0, 0);
        }
    }

    const int cg = lane & 15;
    const int rg = (lane >> 4) * 4;
    #pragma unroll
    for (int t = 0; t < NCT; ++t) {
        int col = t * 16 + cg;
        float bb = 0.f;
        if constexpr (BIAS) bb = bias[col];
        #pragma unroll
        for (int r = 0; r < 4; ++r) {
            int row = row0 + rg + r;
            if (row < M) {
                float v = acc[t][r] + bb;
                if constexpr (RELU) v = fmaxf(v, 0.f);
                C[(size_t)row * LDC + col] = v;
            }
        }
    }
}

// ---------------- CSR build ----------------
__global__ __launch_bounds__(256)
void count_kernel(const int* __restrict__ dst, int E, int* __restrict__ deg)
{
    int i = blockIdx.x * 256 + threadIdx.x;
    if (i < E) atomicAdd(&deg[dst[i]], 1);
}

__global__ __launch_bounds__(256)
void scan_a_kernel(const int* __restrict__ deg, int N,
                   int* __restrict__ locEx, int* __restrict__ blockSums)
{
    __shared__ int buf[256];
    const int t = threadIdx.x;
    const int base = blockIdx.x * 1024 + t * 4;
    int v[4];
    #pragma unroll
    for (int j = 0; j < 4; ++j) v[j] = (base + j < N) ? deg[base + j] : 0;
    const int s = v[0] + v[1] + v[2] + v[3];
    buf[t] = s;
    __syncthreads();
    #pragma unroll
    for (int off = 1; off < 256; off <<= 1) {
        int x = (t >= off) ? buf[t - off] : 0;
        __syncthreads();
        buf[t] += x;
        __syncthreads();
    }
    int run = buf[t] - s;
    if (t == 255) blockSums[blockIdx.x] = buf[255];
    #pragma unroll
    for (int j = 0; j < 4; ++j) {
        if (base + j < N) locEx[base + j] = run;
        run += v[j];
    }
}

__global__ __launch_bounds__(64)
void scan_b_kernel(int* __restrict__ bsum, int nb, int* __restrict__ totalOut)
{
    const int t = threadIdx.x;
    if (nb <= 64) {
        int v = (t < nb) ? bsum[t] : 0;
        int incl = v;
        #pragma unroll
        for (int off = 1; off < 64; off <<= 1) {
            int x = __shfl_up(incl, off, 64);
            if (t >= off) incl += x;
        }
        if (t < nb) bsum[t] = incl - v;
        if (t == 63) *totalOut = incl;
    } else if (t == 0) {
        int run = 0;
        for (int i = 0; i < nb; ++i) { int v = bsum[i]; bsum[i] = run; run += v; }
        *totalOut = run;
    }
}

__global__ __launch_bounds__(256)
void scan_c_kernel(const int* __restrict__ locEx, const int* __restrict__ bsum, int N,
                   int* __restrict__ rowptr, int* __restrict__ cursor)
{
    int i = blockIdx.x * 256 + threadIdx.x;
    if (i < N) {
        int v = locEx[i] + bsum[i >> 10];
        rowptr[i] = v;
        cursor[i] = v;
    }
}

__global__ __launch_bounds__(256)
void fill_kernel(const int* __restrict__ src, const int* __restrict__ dst, int E,
                 int* __restrict__ cursor, int* __restrict__ lists)
{
    int i = blockIdx.x * 256 + threadIdx.x;
    if (i >= E) return;
    int d = dst[i];
    int pos = atomicAdd(&cursor[d], 1);
    lists[pos] = src[i];
}

// ---------------- fused gather + SAGE update ----------------
template<bool BN>
__global__ __launch_bounds__(256)
void gather_update_kernel(const float* __restrict__ Ysrc, const float* __restrict__ Ydst,
                          float* __restrict__ h,
                          const int* __restrict__ rowptr, const int* __restrict__ lists,
                          const float* __restrict__ bl, const float* __restrict__ gamma,
                          const float* __restrict__ beta, const float* __restrict__ mean,
                          const float* __restrict__ var, int N)
{
    const int node = blockIdx.x * 4 + (threadIdx.x >> 6);
    const int c2   = (threadIdx.x & 63) * 2;
    if (node >= N) return;
    const int beg = rowptr[node], end = rowptr[node + 1];

    float ax0 = 0.f, ay0 = 0.f, ax1 = 0.f, ay1 = 0.f;
    int e = beg;
    for (; e + 1 < end; e += 2) {
        int s0 = lists[e], s1 = lists[e + 1];
        float2 v0 = *(const float2*)&Ysrc[(size_t)s0 * 2 * H + c2];
        float2 v1 = *(const float2*)&Ysrc[(size_t)s1 * 2 * H + c2];
        ax0 += v0.x; ay0 += v0.y;
        ax1 += v1.x; ay1 += v1.y;
    }
    if (e < end) {
        int s0 = lists[e];
        float2 v0 = *(const float2*)&Ysrc[(size_t)s0 * 2 * H + c2];
        ax0 += v0.x; ay0 += v0.y;
    }
    ax0 += ax1; ay0 += ay1;
    const float sc = (end > beg) ? 1.0f / (float)(end - beg) : 0.f;

    float2 yv = *(const float2*)&Ydst[(size_t)node * 2 * H + H + c2];
    float2 hv = *(const float2*)&h[(size_t)node * H + c2];

    float u0 = (hv.x + ax0 * sc + yv.x + bl[c2])     * 0.5f;
    float u1 = (hv.y + ay0 * sc + yv.y + bl[c2 + 1]) * 0.5f;
    if constexpr (BN) {
        u0 = (u0 - mean[c2])     * rsqrtf(var[c2]     + 1e-5f) * gamma[c2]     + beta[c2];
        u1 = (u1 - mean[c2 + 1]) * rsqrtf(var[c2 + 1] + 1e-5f) * gamma[c2 + 1] + beta[c2 + 1];
    }
    float2 o = make_float2(fmaxf(u0, 0.f), fmaxf(u1, 0.f));
    *(float2*)&h[(size_t)node * H + c2] = o;
}

extern "C" void kernel_launch(void* const* d_in, const int* in_sizes, int n_in,
                              void* d_out, int out_size, void* d_ws, size_t ws_size,
                              hipStream_t stream)
{
    const float* x_u   = (const float*)d_in[0];
    const float* x_i   = (const float*)d_in[1];
    const int*   iu_src = (const int*)d_in[2];
    const int*   iu_dst = (const int*)d_in[3];
    const int*   ui_src = (const int*)d_in[4];
    const int*   ui_dst = (const int*)d_in[5];
    const float* Wp_u  = (const float*)d_in[6];
    const float* bp_u  = (const float*)d_in[7];
    const float* Wp_i  = (const float*)d_in[8];
    const float* bp_i  = (const float*)d_in[9];
    const float* Wl    = (const float*)d_in[10];
    const float* bl    = (const float*)d_in[11];
    const float* Wr    = (const float*)d_in[12];
    const float* gamma = (const float*)d_in[13];
    const float* beta  = (const float*)d_in[14];
    const float* mean  = (const float*)d_in[15];
    const float* var   = (const float*)d_in[16];
    const float* Wh    = (const float*)d_in[17];
    const float* bh    = (const float*)d_in[18];

    const int N_U = in_sizes[0] / 128;      // 50000
    const int N_I = in_sizes[1] / 64;       // 30000
    const int E   = in_sizes[2];            // 500000
    const int L   = in_sizes[10] / (H * H); // 2
    const int OUT = 32;

    float* out = (float*)d_out;
    float* h_u = out + (size_t)N_U * OUT;   // h_u lives in its output slot

    // workspace layout
    float* ws   = (float*)d_ws;
    float* h_i  = ws;                               // [N_I, 128]
    float* Y_u  = h_i + (size_t)N_I * H;            // [N_U, 256]
    float* Y_i  = Y_u + (size_t)N_U * 2 * H;        // [N_I, 256]
    int*   ip   = (int*)(Y_i + (size_t)N_I * 2 * H);
    int* degU    = ip;               ip += N_U;
    int* degI    = ip;               ip += N_I;
    int* rowU    = ip;               ip += N_U + 1;
    int* rowI    = ip;               ip += N_I + 1;
    int* curU    = ip;               ip += N_U;
    int* curI    = ip;               ip += N_I;
    int* listsU  = ip;               ip += E;
    int* listsI  = ip;               ip += E;
    int* locEx   = ip;               ip += (N_U > N_I ? N_U : N_I);
    int* bsum    = ip;               ip += 128;
    // packed weights (bf16), 16B-aligned
    ushort* up   = (ushort*)(((uintptr_t)ip + 15) & ~(uintptr_t)15);
    ushort* pPu  = up;               up += 4 * 8  * 64 * 8;   // K=128, NCT=8
    ushort* pPi  = up;               up += 2 * 8  * 64 * 8;   // K=64,  NCT=8
    ushort* pL0  = up;               up += 4 * 16 * 64 * 8;   // K=128, NCT=16
    ushort* pL1  = up;               up += 4 * 16 * 64 * 8;
    ushort* pH   = up;               up += 4 * 2  * 64 * 8;   // K=128, NCT=2

    const int nbU = (N_U + 1023) / 1024;
    const int nbI = (N_I + 1023) / 1024;

    // ---- pack weights into MFMA fragment order ----
    pack_w_kernel<<<(4 * 8 * 64 + 255) / 256, 256, 0, stream>>>(Wp_u, 128, 4, 0, 8, 8, pPu);
    pack_w_kernel<<<(2 * 8 * 64 + 255) / 256, 256, 0, stream>>>(Wp_i, 128, 2, 0, 8, 8, pPi);
    for (int l = 0; l < L; ++l) {
        ushort* pL = (l == 0) ? pL0 : pL1;
        pack_w_kernel<<<(4 * 8 * 64 + 255) / 256, 256, 0, stream>>>(
            Wl + (size_t)l * H * H, 128, 4, 0, 8, 16, pL);
        pack_w_kernel<<<(4 * 8 * 64 + 255) / 256, 256, 0, stream>>>(
            Wr + (size_t)l * H * H, 128, 4, 8, 8, 16, pL);
    }
    pack_w_kernel<<<(4 * 2 * 64 + 255) / 256, 256, 0, stream>>>(Wh, 32, 4, 0, 2, 2, pH);

    // ---- CSR build ----
    hipMemsetAsync(degU, 0, (size_t)(N_U + N_I) * sizeof(int), stream);
    count_kernel<<<(E + 255) / 256, 256, 0, stream>>>(iu_dst, E, degU);
    count_kernel<<<(E + 255) / 256, 256, 0, stream>>>(ui_dst, E, degI);

    scan_a_kernel<<<nbU, 256, 0, stream>>>(degU, N_U, locEx, bsum);
    scan_b_kernel<<<1, 64, 0, stream>>>(bsum, nbU, rowU + N_U);
    scan_c_kernel<<<(N_U + 255) / 256, 256, 0, stream>>>(locEx, bsum, N_U, rowU, curU);
    fill_kernel<<<(E + 255) / 256, 256, 0, stream>>>(iu_src, iu_dst, E, curU, listsU);

    scan_a_kernel<<<nbI, 256, 0, stream>>>(degI, N_I, locEx, bsum);
    scan_b_kernel<<<1, 64, 0, stream>>>(bsum, nbI, rowI + N_I);
    scan_c_kernel<<<(N_I + 255) / 256, 256, 0, stream>>>(locEx, bsum, N_I, rowI, curI);
    fill_kernel<<<(E + 255) / 256, 256, 0, stream>>>(ui_src, ui_dst, E, curI, listsI);

    // ---- input projections (+bias, relu) ----
    mfma_gemm_kernel<128, 8, true, true>
        <<<(N_U + 63) / 64, 256, 0, stream>>>(x_u, pPu, bp_u, h_u, N_U);
    mfma_gemm_kernel<64, 8, true, true>
        <<<(N_I + 63) / 64, 256, 0, stream>>>(x_i, pPi, bp_i, h_i, N_I);

    for (int l = 0; l < L; ++l) {
        const ushort* pL = (l == 0) ? pL0 : pL1;
        // Y = h @ [Wl | Wr]   (seg_mean(h)@Wl == seg_mean(h@Wl), by linearity)
        mfma_gemm_kernel<128, 16, false, false>
            <<<(N_U + 63) / 64, 256, 0, stream>>>(h_u, pL, nullptr, Y_u, N_U);
        mfma_gemm_kernel<128, 16, false, false>
            <<<(N_I + 63) / 64, 256, 0, stream>>>(h_i, pL, nullptr, Y_i, N_I);
        gather_update_kernel<true><<<(N_U + 3) / 4, 256, 0, stream>>>(
            Y_i, Y_u, h_u, rowU, listsU,
            bl + l * H, gamma + l * H, beta + l * H, mean + l * H, var + l * H, N_U);
        gather_update_kernel<false><<<(N_I + 3) / 4, 256, 0, stream>>>(
            Y_u, Y_i, h_i, rowI, listsI,
            bl + l * H, nullptr, nullptr, nullptr, nullptr, N_I);
    }

    // ---- head: out0 = h_u @ Wh + bh (h_u already in place as out1) ----
    mfma_gemm_kernel<128, 2, true, false>
        <<<(N_U + 63) / 64, 256, 0, stream>>>(h_u, pH, bh, out, N_U);
}

// Round 5
// 392.336 us; speedup vs baseline: 9.7160x; 1.0914x over previous
//
#include <hip/hip_runtime.h>

constexpr int H = 128;

typedef short bf16x8 __attribute__((ext_vector_type(8)));
typedef float f32x4  __attribute__((ext_vector_type(4)));

__device__ __forceinline__ ushort f2b(float f) {
    uint u = __float_as_uint(f);
    u += 0x7fff + ((u >> 16) & 1);      // round-to-nearest-even
    return (ushort)(u >> 16);
}
__device__ __forceinline__ float b2f(ushort b) {
    return __uint_as_float((uint)b << 16);
}

// ---------------- W pack: frag[s][t0+t][lane][j] = W[s*32 + 8*(l/16) + j][t*16 + l%16]
__global__ __launch_bounds__(256)
void pack_w_kernel(const float* __restrict__ W, int ldw, int S, int t0, int nct,
                   int nctTot, ushort* __restrict__ dst)
{
    int f = blockIdx.x * 256 + threadIdx.x;
    int total = S * nct * 64;
    if (f >= total) return;
    int l = f & 63;
    int t = (f >> 6) % nct;
    int s = (f >> 6) / nct;
    int col = t * 16 + (l & 15);
    int kb  = s * 32 + (l >> 4) * 8;
    ushort o[8];
    #pragma unroll
    for (int j = 0; j < 8; ++j) o[j] = f2b(W[(size_t)(kb + j) * ldw + col]);
    ushort* d = dst + ((size_t)(s * nctTot + t0 + t) * 64 + l) * 8;
    *(uint4*)d = *(uint4*)o;
}

// ---------------- MFMA GEMM: C[M, NCT*16] = act(A[M,K] @ Wpack (+bias)) ------
// 256 threads = 4 waves; wave w computes rows [blk*64 + 16w, +16) x all NCT*16 cols.
// A fp32 row-major converted inline to bf16; Wpack in fragment order.
// OBF16: write output as bf16 (ushort) instead of fp32.
template<int K, int NCT, bool BIAS, bool RELU, bool OBF16>
__global__ __launch_bounds__(256)
void mfma_gemm_kernel(const float* __restrict__ A, const ushort* __restrict__ Wp,
                      const float* __restrict__ bias, void* __restrict__ Cv, int M)
{
    constexpr int S   = K / 32;
    constexpr int LDC = NCT * 16;
    const int wave = threadIdx.x >> 6;
    const int lane = threadIdx.x & 63;
    const int row0 = blockIdx.x * 64 + wave * 16;

    int ar = row0 + (lane & 15);
    if (ar >= M) ar = M - 1;                      // clamp loads; stores guarded
    const float* arow = A + (size_t)ar * K + (lane >> 4) * 8;
    const bf16x8* W8  = (const bf16x8*)Wp;

    f32x4 acc[NCT];
    #pragma unroll
    for (int t = 0; t < NCT; ++t) acc[t] = (f32x4){0.f, 0.f, 0.f, 0.f};

    #pragma unroll
    for (int s = 0; s < S; ++s) {
        float4 f0 = *(const float4*)(arow + s * 32);
        float4 f1 = *(const float4*)(arow + s * 32 + 4);
        bf16x8 a;
        a[0] = (short)f2b(f0.x); a[1] = (short)f2b(f0.y);
        a[2] = (short)f2b(f0.z); a[3] = (short)f2b(f0.w);
        a[4] = (short)f2b(f1.x); a[5] = (short)f2b(f1.y);
        a[6] = (short)f2b(f1.z); a[7] = (short)f2b(f1.w);
        #pragma unroll
        for (int t = 0; t < NCT; ++t) {
            bf16x8 b = W8[(size_t)(s * NCT + t) * 64 + lane];
            acc[t] = __builtin_amdgcn_mfma_f32_16x16x32_bf16(a, b, acc[t], 0, 0, 0);
        }
    }

    const int cg = lane & 15;
    const int rg = (lane >> 4) * 4;
    #pragma unroll
    for (int t = 0; t < NCT; ++t) {
        int col = t * 16 + cg;
        float bb = 0.f;
        if constexpr (BIAS) bb = bias[col];
        #pragma unroll
        for (int r = 0; r < 4; ++r) {
            int row = row0 + rg + r;
            if (row < M) {
                float v = acc[t][r] + bb;
                if constexpr (RELU) v = fmaxf(v, 0.f);
                if constexpr (OBF16)
                    ((ushort*)Cv)[(size_t)row * LDC + col] = f2b(v);
                else
                    ((float*)Cv)[(size_t)row * LDC + col] = v;
            }
        }
    }
}

// ---------------- CSR build ----------------
__global__ __launch_bounds__(256)
void count_kernel(const int* __restrict__ dst, int E, int* __restrict__ deg)
{
    int i = blockIdx.x * 256 + threadIdx.x;
    if (i < E) atomicAdd(&deg[dst[i]], 1);
}

__global__ __launch_bounds__(256)
void scan_a_kernel(const int* __restrict__ deg, int N,
                   int* __restrict__ locEx, int* __restrict__ blockSums)
{
    __shared__ int buf[256];
    const int t = threadIdx.x;
    const int base = blockIdx.x * 1024 + t * 4;
    int v[4];
    #pragma unroll
    for (int j = 0; j < 4; ++j) v[j] = (base + j < N) ? deg[base + j] : 0;
    const int s = v[0] + v[1] + v[2] + v[3];
    buf[t] = s;
    __syncthreads();
    #pragma unroll
    for (int off = 1; off < 256; off <<= 1) {
        int x = (t >= off) ? buf[t - off] : 0;
        __syncthreads();
        buf[t] += x;
        __syncthreads();
    }
    int run = buf[t] - s;
    if (t == 255) blockSums[blockIdx.x] = buf[255];
    #pragma unroll
    for (int j = 0; j < 4; ++j) {
        if (base + j < N) locEx[base + j] = run;
        run += v[j];
    }
}

__global__ __launch_bounds__(64)
void scan_b_kernel(int* __restrict__ bsum, int nb, int* __restrict__ totalOut)
{
    const int t = threadIdx.x;
    if (nb <= 64) {
        int v = (t < nb) ? bsum[t] : 0;
        int incl = v;
        #pragma unroll
        for (int off = 1; off < 64; off <<= 1) {
            int x = __shfl_up(incl, off, 64);
            if (t >= off) incl += x;
        }
        if (t < nb) bsum[t] = incl - v;
        if (t == 63) *totalOut = incl;
    } else if (t == 0) {
        int run = 0;
        for (int i = 0; i < nb; ++i) { int v = bsum[i]; bsum[i] = run; run += v; }
        *totalOut = run;
    }
}

__global__ __launch_bounds__(256)
void scan_c_kernel(const int* __restrict__ locEx, const int* __restrict__ bsum, int N,
                   int* __restrict__ rowptr, int* __restrict__ cursor)
{
    int i = blockIdx.x * 256 + threadIdx.x;
    if (i < N) {
        int v = locEx[i] + bsum[i >> 10];
        rowptr[i] = v;
        cursor[i] = v;
    }
}

__global__ __launch_bounds__(256)
void fill_kernel(const int* __restrict__ src, const int* __restrict__ dst, int E,
                 int* __restrict__ cursor, int* __restrict__ lists)
{
    int i = blockIdx.x * 256 + threadIdx.x;
    if (i >= E) return;
    int d = dst[i];
    int pos = atomicAdd(&cursor[d], 1);
    lists[pos] = src[i];
}

// ---------------- fused gather + SAGE update (Y in bf16) ----------------
// One 64-lane wave per dst node; lane owns 2 consecutive cols (ushort2 = 4 B).
template<bool BN>
__global__ __launch_bounds__(256)
void gather_update_kernel(const ushort* __restrict__ Ysrc, const ushort* __restrict__ Ydst,
                          float* __restrict__ h,
                          const int* __restrict__ rowptr, const int* __restrict__ lists,
                          const float* __restrict__ bl, const float* __restrict__ gamma,
                          const float* __restrict__ beta, const float* __restrict__ mean,
                          const float* __restrict__ var, int N)
{
    const int node = blockIdx.x * 4 + (threadIdx.x >> 6);
    const int c2   = (threadIdx.x & 63) * 2;
    if (node >= N) return;
    const int beg = rowptr[node], end = rowptr[node + 1];

    float ax0 = 0.f, ay0 = 0.f, ax1 = 0.f, ay1 = 0.f;
    int e = beg;
    for (; e + 1 < end; e += 2) {
        int s0 = lists[e], s1 = lists[e + 1];
        uint v0 = *(const uint*)&Ysrc[(size_t)s0 * 2 * H + c2];
        uint v1 = *(const uint*)&Ysrc[(size_t)s1 * 2 * H + c2];
        ax0 += b2f((ushort)v0); ay0 += b2f((ushort)(v0 >> 16));
        ax1 += b2f((ushort)v1); ay1 += b2f((ushort)(v1 >> 16));
    }
    if (e < end) {
        int s0 = lists[e];
        uint v0 = *(const uint*)&Ysrc[(size_t)s0 * 2 * H + c2];
        ax0 += b2f((ushort)v0); ay0 += b2f((ushort)(v0 >> 16));
    }
    ax0 += ax1; ay0 += ay1;
    const float sc = (end > beg) ? 1.0f / (float)(end - beg) : 0.f;

    uint yv = *(const uint*)&Ydst[(size_t)node * 2 * H + H + c2];
    float2 hv = *(const float2*)&h[(size_t)node * H + c2];

    float u0 = (hv.x + ax0 * sc + b2f((ushort)yv)         + bl[c2])     * 0.5f;
    float u1 = (hv.y + ay0 * sc + b2f((ushort)(yv >> 16)) + bl[c2 + 1]) * 0.5f;
    if constexpr (BN) {
        u0 = (u0 - mean[c2])     * rsqrtf(var[c2]     + 1e-5f) * gamma[c2]     + beta[c2];
        u1 = (u1 - mean[c2 + 1]) * rsqrtf(var[c2 + 1] + 1e-5f) * gamma[c2 + 1] + beta[c2 + 1];
    }
    float2 o = make_float2(fmaxf(u0, 0.f), fmaxf(u1, 0.f));
    *(float2*)&h[(size_t)node * H + c2] = o;
}

extern "C" void kernel_launch(void* const* d_in, const int* in_sizes, int n_in,
                              void* d_out, int out_size, void* d_ws, size_t ws_size,
                              hipStream_t stream)
{
    const float* x_u   = (const float*)d_in[0];
    const float* x_i   = (const float*)d_in[1];
    const int*   iu_src = (const int*)d_in[2];
    const int*   iu_dst = (const int*)d_in[3];
    const int*   ui_src = (const int*)d_in[4];
    const int*   ui_dst = (const int*)d_in[5];
    const float* Wp_u  = (const float*)d_in[6];
    const float* bp_u  = (const float*)d_in[7];
    const float* Wp_i  = (const float*)d_in[8];
    const float* bp_i  = (const float*)d_in[9];
    const float* Wl    = (const float*)d_in[10];
    const float* bl    = (const float*)d_in[11];
    const float* Wr    = (const float*)d_in[12];
    const float* gamma = (const float*)d_in[13];
    const float* beta  = (const float*)d_in[14];
    const float* mean  = (const float*)d_in[15];
    const float* var   = (const float*)d_in[16];
    const float* Wh    = (const float*)d_in[17];
    const float* bh    = (const float*)d_in[18];

    const int N_U = in_sizes[0] / 128;      // 50000
    const int N_I = in_sizes[1] / 64;       // 30000
    const int E   = in_sizes[2];            // 500000
    const int L   = in_sizes[10] / (H * H); // 2
    const int OUT = 32;

    float* out = (float*)d_out;
    float* h_u = out + (size_t)N_U * OUT;   // h_u lives in its output slot

    // workspace layout
    float*  ws   = (float*)d_ws;
    float*  h_i  = ws;                              // [N_I,128] fp32
    ushort* Y_u  = (ushort*)(h_i + (size_t)N_I * H);  // [N_U,256] bf16
    ushort* Y_i  = Y_u + (size_t)N_U * 2 * H;         // [N_I,256] bf16
    int*    ip   = (int*)(((uintptr_t)(Y_i + (size_t)N_I * 2 * H) + 15) & ~(uintptr_t)15);
    int* degU    = ip;               ip += N_U;
    int* degI    = ip;               ip += N_I;
    int* rowU    = ip;               ip += N_U + 1;
    int* rowI    = ip;               ip += N_I + 1;
    int* curU    = ip;               ip += N_U;
    int* curI    = ip;               ip += N_I;
    int* listsU  = ip;               ip += E;
    int* listsI  = ip;               ip += E;
    int* locEx   = ip;               ip += (N_U > N_I ? N_U : N_I);
    int* bsum    = ip;               ip += 128;
    // packed weights (bf16), 16B-aligned
    ushort* up   = (ushort*)(((uintptr_t)ip + 15) & ~(uintptr_t)15);
    ushort* pPu  = up;               up += 4 * 8  * 64 * 8;   // K=128, NCT=8
    ushort* pPi  = up;               up += 2 * 8  * 64 * 8;   // K=64,  NCT=8
    ushort* pL0  = up;               up += 4 * 16 * 64 * 8;   // K=128, NCT=16
    ushort* pL1  = up;               up += 4 * 16 * 64 * 8;
    ushort* pH   = up;               up += 4 * 2  * 64 * 8;   // K=128, NCT=2

    const int nbU = (N_U + 1023) / 1024;
    const int nbI = (N_I + 1023) / 1024;

    // ---- pack weights into MFMA fragment order ----
    pack_w_kernel<<<(4 * 8 * 64 + 255) / 256, 256, 0, stream>>>(Wp_u, 128, 4, 0, 8, 8, pPu);
    pack_w_kernel<<<(2 * 8 * 64 + 255) / 256, 256, 0, stream>>>(Wp_i, 128, 2, 0, 8, 8, pPi);
    for (int l = 0; l < L; ++l) {
        ushort* pL = (l == 0) ? pL0 : pL1;
        pack_w_kernel<<<(4 * 8 * 64 + 255) / 256, 256, 0, stream>>>(
            Wl + (size_t)l * H * H, 128, 4, 0, 8, 16, pL);
        pack_w_kernel<<<(4 * 8 * 64 + 255) / 256, 256, 0, stream>>>(
            Wr + (size_t)l * H * H, 128, 4, 8, 8, 16, pL);
    }
    pack_w_kernel<<<(4 * 2 * 64 + 255) / 256, 256, 0, stream>>>(Wh, 32, 4, 0, 2, 2, pH);

    // ---- CSR build ----
    hipMemsetAsync(degU, 0, (size_t)(N_U + N_I) * sizeof(int), stream);
    count_kernel<<<(E + 255) / 256, 256, 0, stream>>>(iu_dst, E, degU);
    count_kernel<<<(E + 255) / 256, 256, 0, stream>>>(ui_dst, E, degI);

    scan_a_kernel<<<nbU, 256, 0, stream>>>(degU, N_U, locEx, bsum);
    scan_b_kernel<<<1, 64, 0, stream>>>(bsum, nbU, rowU + N_U);
    scan_c_kernel<<<(N_U + 255) / 256, 256, 0, stream>>>(locEx, bsum, N_U, rowU, curU);
    fill_kernel<<<(E + 255) / 256, 256, 0, stream>>>(iu_src, iu_dst, E, curU, listsU);

    scan_a_kernel<<<nbI, 256, 0, stream>>>(degI, N_I, locEx, bsum);
    scan_b_kernel<<<1, 64, 0, stream>>>(bsum, nbI, rowI + N_I);
    scan_c_kernel<<<(N_I + 255) / 256, 256, 0, stream>>>(locEx, bsum, N_I, rowI, curI);
    fill_kernel<<<(E + 255) / 256, 256, 0, stream>>>(ui_src, ui_dst, E, curI, listsI);

    // ---- input projections (+bias, relu) -> fp32 h ----
    mfma_gemm_kernel<128, 8, true, true, false>
        <<<(N_U + 63) / 64, 256, 0, stream>>>(x_u, pPu, bp_u, h_u, N_U);
    mfma_gemm_kernel<64, 8, true, true, false>
        <<<(N_I + 63) / 64, 256, 0, stream>>>(x_i, pPi, bp_i, h_i, N_I);

    for (int l = 0; l < L; ++l) {
        const ushort* pL = (l == 0) ? pL0 : pL1;
        // Y = h @ [Wl | Wr] -> bf16   (seg_mean(h)@Wl == seg_mean(h@Wl))
        mfma_gemm_kernel<128, 16, false, false, true>
            <<<(N_U + 63) / 64, 256, 0, stream>>>(h_u, pL, nullptr, Y_u, N_U);
        mfma_gemm_kernel<128, 16, false, false, true>
            <<<(N_I + 63) / 64, 256, 0, stream>>>(h_i, pL, nullptr, Y_i, N_I);
        gather_update_kernel<true><<<(N_U + 3) / 4, 256, 0, stream>>>(
            Y_i, Y_u, h_u, rowU, listsU,
            bl + l * H, gamma + l * H, beta + l * H, mean + l * H, var + l * H, N_U);
        gather_update_kernel<false><<<(N_I + 3) / 4, 256, 0, stream>>>(
            Y_u, Y_i, h_i, rowI, listsI,
            bl + l * H, nullptr, nullptr, nullptr, nullptr, N_I);
    }

    // ---- head: out0 = h_u @ Wh + bh (h_u already in place as out1) ----
    mfma_gemm_kernel<128, 2, true, false, false>
        <<<(N_U + 63) / 64, 256, 0, stream>>>(h_u, pH, bh, out, N_U);
}

// Round 6
// 327.663 us; speedup vs baseline: 11.6337x; 1.1974x over previous
//
#include <hip/hip_runtime.h>

constexpr int H = 128;

typedef short bf16x8 __attribute__((ext_vector_type(8)));
typedef float f32x4  __attribute__((ext_vector_type(4)));

__device__ __forceinline__ ushort f2b(float f) {
    uint u = __float_as_uint(f);
    u += 0x7fff + ((u >> 16) & 1);      // round-to-nearest-even
    return (ushort)(u >> 16);
}
__device__ __forceinline__ float b2f(ushort b) {
    return __uint_as_float((uint)b << 16);
}

// ---------------- W pack (generic, fallback): frag[s][t0+t][lane][j] ----------
__device__ __forceinline__ void pack_one(const float* __restrict__ W, int ldw,
                                         int t0, int nct, int nctTot,
                                         ushort* __restrict__ dst, int fgl, int l)
{
    int t = fgl % nct, s = fgl / nct;
    int col = t * 16 + (l & 15);
    int kb  = s * 32 + (l >> 4) * 8;
    ushort o[8];
    #pragma unroll
    for (int j = 0; j < 8; ++j) o[j] = f2b(W[(size_t)(kb + j) * ldw + col]);
    ushort* d = dst + ((size_t)(s * nctTot + t0 + t) * 64 + l) * 8;
    *(uint4*)d = *(uint4*)o;
}

__global__ __launch_bounds__(256)
void pack_w_kernel(const float* __restrict__ W, int ldw, int S, int t0, int nct,
                   int nctTot, ushort* __restrict__ dst)
{
    int f = blockIdx.x * 256 + threadIdx.x;
    if (f >= S * nct * 64) return;
    pack_one(W, ldw, t0, nct, nctTot, dst, f >> 6, f & 63);
}

// ---------------- all-weights pack in one launch (L == 2) ----------------
__global__ __launch_bounds__(256)
void pack_all_kernel(const float* __restrict__ Wp_u, const float* __restrict__ Wp_i,
                     const float* __restrict__ Wl, const float* __restrict__ Wr,
                     const float* __restrict__ Wh,
                     ushort* __restrict__ pPu, ushort* __restrict__ pPi,
                     ushort* __restrict__ pL0, ushort* __restrict__ pL1,
                     ushort* __restrict__ pH)
{
    int f = blockIdx.x * 256 + threadIdx.x;
    int fg = f >> 6, l = f & 63;
    // segments (frag-groups): [0,32) Pu | [32,48) Pi | [48,80) L0l | [80,112) L0r
    //                         [112,144) L1l | [144,176) L1r | [176,184) head
    if (fg < 32)       pack_one(Wp_u,          128, 0, 8, 8,  pPu, fg,       l);
    else if (fg < 48)  pack_one(Wp_i,          128, 0, 8, 8,  pPi, fg - 32,  l);
    else if (fg < 80)  pack_one(Wl,            128, 0, 8, 16, pL0, fg - 48,  l);
    else if (fg < 112) pack_one(Wr,            128, 8, 8, 16, pL0, fg - 80,  l);
    else if (fg < 144) pack_one(Wl + H * H,    128, 0, 8, 16, pL1, fg - 112, l);
    else if (fg < 176) pack_one(Wr + H * H,    128, 8, 8, 16, pL1, fg - 144, l);
    else if (fg < 184) pack_one(Wh,             32, 0, 2, 2,  pH,  fg - 176, l);
}

// ---------------- MFMA GEMM body + merged-pair kernel ----------------
template<int K, int NCT, bool BIAS, bool RELU, bool OBF16>
__device__ __forceinline__ void mfma_gemm_body(
    const float* __restrict__ A, const ushort* __restrict__ Wp,
    const float* __restrict__ bias, void* __restrict__ Cv, int M, int blk)
{
    constexpr int S   = K / 32;
    constexpr int LDC = NCT * 16;
    const int wave = threadIdx.x >> 6;
    const int lane = threadIdx.x & 63;
    const int row0 = blk * 64 + wave * 16;

    int ar = row0 + (lane & 15);
    if (ar >= M) ar = M - 1;                      // clamp loads; stores guarded
    const float* arow = A + (size_t)ar * K + (lane >> 4) * 8;
    const bf16x8* W8  = (const bf16x8*)Wp;

    f32x4 acc[NCT];
    #pragma unroll
    for (int t = 0; t < NCT; ++t) acc[t] = (f32x4){0.f, 0.f, 0.f, 0.f};

    #pragma unroll
    for (int s = 0; s < S; ++s) {
        float4 f0 = *(const float4*)(arow + s * 32);
        float4 f1 = *(const float4*)(arow + s * 32 + 4);
        bf16x8 a;
        a[0] = (short)f2b(f0.x); a[1] = (short)f2b(f0.y);
        a[2] = (short)f2b(f0.z); a[3] = (short)f2b(f0.w);
        a[4] = (short)f2b(f1.x); a[5] = (short)f2b(f1.y);
        a[6] = (short)f2b(f1.z); a[7] = (short)f2b(f1.w);
        #pragma unroll
        for (int t = 0; t < NCT; ++t) {
            bf16x8 b = W8[(size_t)(s * NCT + t) * 64 + lane];
            acc[t] = __builtin_amdgcn_mfma_f32_16x16x32_bf16(a, b, acc[t], 0, 0, 0);
        }
    }

    const int cg = lane & 15;
    const int rg = (lane >> 4) * 4;
    #pragma unroll
    for (int t = 0; t < NCT; ++t) {
        int col = t * 16 + cg;
        float bb = 0.f;
        if constexpr (BIAS) bb = bias[col];
        #pragma unroll
        for (int r = 0; r < 4; ++r) {
            int row = row0 + rg + r;
            if (row < M) {
                float v = acc[t][r] + bb;
                if constexpr (RELU) v = fmaxf(v, 0.f);
                if constexpr (OBF16)
                    ((ushort*)Cv)[(size_t)row * LDC + col] = f2b(v);
                else
                    ((float*)Cv)[(size_t)row * LDC + col] = v;
            }
        }
    }
}

template<int K, int NCT, bool BIAS, bool RELU, bool OBF16>
__global__ __launch_bounds__(256)
void mfma_gemm2_kernel(const float* __restrict__ A0, const ushort* __restrict__ Wp,
                       const float* __restrict__ bias, void* __restrict__ C0,
                       int M0, int nb0,
                       const float* __restrict__ A1, void* __restrict__ C1, int M1)
{
    if ((int)blockIdx.x < nb0)
        mfma_gemm_body<K, NCT, BIAS, RELU, OBF16>(A0, Wp, bias, C0, M0, blockIdx.x);
    else
        mfma_gemm_body<K, NCT, BIAS, RELU, OBF16>(A1, Wp, bias, C1, M1, blockIdx.x - nb0);
}

// ---------------- CSR build (merged U/I) ----------------
__global__ __launch_bounds__(256)
void count2_kernel(const int* __restrict__ dstU, int* __restrict__ degU,
                   const int* __restrict__ dstI, int* __restrict__ degI, int E)
{
    int i = blockIdx.x * 256 + threadIdx.x;
    if (i < E) atomicAdd(&degU[dstU[i]], 1);
    else if (i < 2 * E) atomicAdd(&degI[dstI[i - E]], 1);
}

__device__ __forceinline__ void scan_a_body(const int* __restrict__ deg, int N,
                                            int* __restrict__ locEx,
                                            int* __restrict__ blockSums, int blk)
{
    __shared__ int buf[256];
    const int t = threadIdx.x;
    const int base = blk * 1024 + t * 4;
    int v[4];
    #pragma unroll
    for (int j = 0; j < 4; ++j) v[j] = (base + j < N) ? deg[base + j] : 0;
    const int s = v[0] + v[1] + v[2] + v[3];
    buf[t] = s;
    __syncthreads();
    #pragma unroll
    for (int off = 1; off < 256; off <<= 1) {
        int x = (t >= off) ? buf[t - off] : 0;
        __syncthreads();
        buf[t] += x;
        __syncthreads();
    }
    int run = buf[t] - s;
    if (t == 255) blockSums[blk] = buf[255];
    #pragma unroll
    for (int j = 0; j < 4; ++j) {
        if (base + j < N) locEx[base + j] = run;
        run += v[j];
    }
}

__global__ __launch_bounds__(256)
void scan_a2_kernel(const int* __restrict__ degU, int N_U, int* __restrict__ locExU,
                    int* __restrict__ bsumU, int nbsU,
                    const int* __restrict__ degI, int N_I, int* __restrict__ locExI,
                    int* __restrict__ bsumI)
{
    if ((int)blockIdx.x < nbsU)
        scan_a_body(degU, N_U, locExU, bsumU, blockIdx.x);
    else
        scan_a_body(degI, N_I, locExI, bsumI, blockIdx.x - nbsU);
}

// one block, 2 waves: wave0 scans U block-sums, wave1 scans I block-sums (nb <= 64)
__global__ __launch_bounds__(128)
void scan_b2_kernel(int* __restrict__ bsumU, int nbU, int* __restrict__ totU,
                    int* __restrict__ bsumI, int nbI, int* __restrict__ totI)
{
    const int w = threadIdx.x >> 6;
    int* bsum = w ? bsumI : bsumU;
    int  nb   = w ? nbI   : nbU;
    int* tot  = w ? totI  : totU;
    const int t = threadIdx.x & 63;
    if (nb <= 64) {
        int v = (t < nb) ? bsum[t] : 0;
        int incl = v;
        #pragma unroll
        for (int off = 1; off < 64; off <<= 1) {
            int x = __shfl_up(incl, off, 64);
            if (t >= off) incl += x;
        }
        if (t < nb) bsum[t] = incl - v;
        if (t == 63) *tot = incl;
    } else if (t == 0) {
        int run = 0;
        for (int i = 0; i < nb; ++i) { int v = bsum[i]; bsum[i] = run; run += v; }
        *tot = run;
    }
}

__global__ __launch_bounds__(256)
void scan_c2_kernel(const int* __restrict__ locExU, const int* __restrict__ bsumU,
                    int N_U, int* __restrict__ rowU, int* __restrict__ curU, int cU,
                    const int* __restrict__ locExI, const int* __restrict__ bsumI,
                    int N_I, int* __restrict__ rowI, int* __restrict__ curI)
{
    int b = blockIdx.x, i;
    const int *locEx, *bsum; int N; int *rowptr, *cursor;
    if (b < cU) { i = b * 256 + threadIdx.x;
                  locEx = locExU; bsum = bsumU; N = N_U; rowptr = rowU; cursor = curU; }
    else        { i = (b - cU) * 256 + threadIdx.x;
                  locEx = locExI; bsum = bsumI; N = N_I; rowptr = rowI; cursor = curI; }
    if (i < N) {
        int v = locEx[i] + bsum[i >> 10];
        rowptr[i] = v;
        cursor[i] = v;
    }
}

__global__ __launch_bounds__(256)
void fill2_kernel(const int* __restrict__ srcU, const int* __restrict__ dstU,
                  int* __restrict__ curU, int* __restrict__ listsU,
                  const int* __restrict__ srcI, const int* __restrict__ dstI,
                  int* __restrict__ curI, int* __restrict__ listsI, int E)
{
    int i = blockIdx.x * 256 + threadIdx.x;
    if (i < E) {
        int d = dstU[i];
        int pos = atomicAdd(&curU[d], 1);
        listsU[pos] = srcU[i];
    } else if (i < 2 * E) {
        i -= E;
        int d = dstI[i];
        int pos = atomicAdd(&curI[d], 1);
        listsI[pos] = srcI[i];
    }
}

// ---------------- fused gather + SAGE update (Y bf16, edge-parallel) --------
// 1 wave per node; 4 groups x 16 lanes; group g handles edges e = beg+g (+4);
// lane owns 8 cols (uint4 = 16 B). Cross-group combine: shfl_xor 16, 32.
template<bool BN>
__device__ __forceinline__ void gather_body(
    const ushort* __restrict__ Ysrc, const ushort* __restrict__ Ydst,
    float* __restrict__ h,
    const int* __restrict__ rowptr, const int* __restrict__ lists,
    const float* __restrict__ bl, const float* __restrict__ gamma,
    const float* __restrict__ beta, const float* __restrict__ mean,
    const float* __restrict__ var, int N, int blk)
{
    const int node = blk * 4 + (threadIdx.x >> 6);
    if (node >= N) return;
    const int lane = threadIdx.x & 63;
    const int grp  = lane >> 4;
    const int c8   = (lane & 15) * 8;

    const int beg = rowptr[node];
    const int end = rowptr[node + 1];

    float s[8] = {0.f, 0.f, 0.f, 0.f, 0.f, 0.f, 0.f, 0.f};
    int e = beg + grp;
    for (; e + 4 < end; e += 8) {                 // 8 edges in flight per wave
        int s0 = lists[e], s1 = lists[e + 4];
        uint4 v0 = *(const uint4*)&Ysrc[(size_t)s0 * 2 * H + c8];
        uint4 v1 = *(const uint4*)&Ysrc[(size_t)s1 * 2 * H + c8];
        s[0] += b2f((ushort)v0.x) + b2f((ushort)v1.x);
        s[1] += b2f((ushort)(v0.x >> 16)) + b2f((ushort)(v1.x >> 16));
        s[2] += b2f((ushort)v0.y) + b2f((ushort)v1.y);
        s[3] += b2f((ushort)(v0.y >> 16)) + b2f((ushort)(v1.y >> 16));
        s[4] += b2f((ushort)v0.z) + b2f((ushort)v1.z);
        s[5] += b2f((ushort)(v0.z >> 16)) + b2f((ushort)(v1.z >> 16));
        s[6] += b2f((ushort)v0.w) + b2f((ushort)v1.w);
        s[7] += b2f((ushort)(v0.w >> 16)) + b2f((ushort)(v1.w >> 16));
    }
    if (e < end) {
        int s0 = lists[e];
        uint4 v0 = *(const uint4*)&Ysrc[(size_t)s0 * 2 * H + c8];
        s[0] += b2f((ushort)v0.x); s[1] += b2f((ushort)(v0.x >> 16));
        s[2] += b2f((ushort)v0.y); s[3] += b2f((ushort)(v0.y >> 16));
        s[4] += b2f((ushort)v0.z); s[5] += b2f((ushort)(v0.z >> 16));
        s[6] += b2f((ushort)v0.w); s[7] += b2f((ushort)(v0.w >> 16));
    }
    #pragma unroll
    for (int j = 0; j < 8; ++j) {
        s[j] += __shfl_xor(s[j], 16, 64);
        s[j] += __shfl_xor(s[j], 32, 64);
    }
    if (grp != 0) return;                          // lanes 0-15 finish the node
    const int deg = end - beg;
    const float sc = (deg > 0) ? 1.0f / (float)deg : 0.f;

    uint4 yv = *(const uint4*)&Ydst[(size_t)node * 2 * H + H + c8];
    float y[8] = { b2f((ushort)yv.x), b2f((ushort)(yv.x >> 16)),
                   b2f((ushort)yv.y), b2f((ushort)(yv.y >> 16)),
                   b2f((ushort)yv.z), b2f((ushort)(yv.z >> 16)),
                   b2f((ushort)yv.w), b2f((ushort)(yv.w >> 16)) };
    float4 h0 = *(const float4*)&h[(size_t)node * H + c8];
    float4 h1 = *(const float4*)&h[(size_t)node * H + c8 + 4];
    float hh[8] = {h0.x, h0.y, h0.z, h0.w, h1.x, h1.y, h1.z, h1.w};
    float o[8];
    #pragma unroll
    for (int j = 0; j < 8; ++j) {
        float u = (hh[j] + s[j] * sc + y[j] + bl[c8 + j]) * 0.5f;
        if constexpr (BN)
            u = (u - mean[c8 + j]) * rsqrtf(var[c8 + j] + 1e-5f) * gamma[c8 + j] + beta[c8 + j];
        o[j] = fmaxf(u, 0.f);
    }
    *(float4*)&h[(size_t)node * H + c8]     = make_float4(o[0], o[1], o[2], o[3]);
    *(float4*)&h[(size_t)node * H + c8 + 4] = make_float4(o[4], o[5], o[6], o[7]);
}

__global__ __launch_bounds__(256)
void gather2_kernel(const ushort* __restrict__ Ys0, const ushort* __restrict__ Yd0,
                    float* __restrict__ h0,
                    const int* __restrict__ rp0, const int* __restrict__ li0,
                    const float* __restrict__ bl, const float* __restrict__ gamma,
                    const float* __restrict__ beta, const float* __restrict__ mean,
                    const float* __restrict__ var, int N0, int nb0,
                    const ushort* __restrict__ Ys1, const ushort* __restrict__ Yd1,
                    float* __restrict__ h1,
                    const int* __restrict__ rp1, const int* __restrict__ li1, int N1)
{
    if ((int)blockIdx.x < nb0)
        gather_body<true>(Ys0, Yd0, h0, rp0, li0, bl, gamma, beta, mean, var, N0, blockIdx.x);
    else
        gather_body<false>(Ys1, Yd1, h1, rp1, li1, bl, gamma, beta, mean, var, N1,
                           blockIdx.x - nb0);
}

extern "C" void kernel_launch(void* const* d_in, const int* in_sizes, int n_in,
                              void* d_out, int out_size, void* d_ws, size_t ws_size,
                              hipStream_t stream)
{
    const float* x_u   = (const float*)d_in[0];
    const float* x_i   = (const float*)d_in[1];
    const int*   iu_src = (const int*)d_in[2];
    const int*   iu_dst = (const int*)d_in[3];
    const int*   ui_src = (const int*)d_in[4];
    const int*   ui_dst = (const int*)d_in[5];
    const float* Wp_u  = (const float*)d_in[6];
    const float* bp_u  = (const float*)d_in[7];
    const float* Wp_i  = (const float*)d_in[8];
    const float* bp_i  = (const float*)d_in[9];
    const float* Wl    = (const float*)d_in[10];
    const float* bl    = (const float*)d_in[11];
    const float* Wr    = (const float*)d_in[12];
    const float* gamma = (const float*)d_in[13];
    const float* beta  = (const float*)d_in[14];
    const float* mean  = (const float*)d_in[15];
    const float* var   = (const float*)d_in[16];
    const float* Wh    = (const float*)d_in[17];
    const float* bh    = (const float*)d_in[18];

    const int N_U = in_sizes[0] / 128;      // 50000
    const int N_I = in_sizes[1] / 64;       // 30000
    const int E   = in_sizes[2];            // 500000
    const int L   = in_sizes[10] / (H * H); // 2
    const int OUT = 32;

    float* out = (float*)d_out;
    float* h_u = out + (size_t)N_U * OUT;   // h_u lives in its output slot

    // workspace layout
    float*  ws   = (float*)d_ws;
    float*  h_i  = ws;                                // [N_I,128] fp32
    ushort* Y_u  = (ushort*)(h_i + (size_t)N_I * H);  // [N_U,256] bf16
    ushort* Y_i  = Y_u + (size_t)N_U * 2 * H;         // [N_I,256] bf16
    int*    ip   = (int*)(((uintptr_t)(Y_i + (size_t)N_I * 2 * H) + 15) & ~(uintptr_t)15);
    int* degU    = ip;               ip += N_U;
    int* degI    = ip;               ip += N_I;
    int* rowU    = ip;               ip += N_U + 1;
    int* rowI    = ip;               ip += N_I + 1;
    int* curU    = ip;               ip += N_U;
    int* curI    = ip;               ip += N_I;
    int* listsU  = ip;               ip += E;
    int* listsI  = ip;               ip += E;
    int* locExU  = ip;               ip += N_U;
    int* locExI  = ip;               ip += N_I;
    int* bsumU   = ip;               ip += 64;
    int* bsumI   = ip;               ip += 64;
    // packed weights (bf16), 16B-aligned
    ushort* up   = (ushort*)(((uintptr_t)ip + 15) & ~(uintptr_t)15);
    ushort* pPu  = up;               up += 4 * 8  * 64 * 8;   // K=128, NCT=8
    ushort* pPi  = up;               up += 2 * 8  * 64 * 8;   // K=64,  NCT=8
    ushort* pL0  = up;               up += 4 * 16 * 64 * 8;   // K=128, NCT=16
    ushort* pL1  = up;               up += 4 * 16 * 64 * 8;
    ushort* pH   = up;               up += 4 * 2  * 64 * 8;   // K=128, NCT=2

    const int nbsU = (N_U + 1023) / 1024;   // scan_a blocks
    const int nbsI = (N_I + 1023) / 1024;
    const int gU   = (N_U + 63) / 64;       // gemm blocks
    const int gI   = (N_I + 63) / 64;
    const int aU   = (N_U + 3) / 4;         // gather blocks
    const int aI   = (N_I + 3) / 4;
    const int cU   = (N_U + 255) / 256;     // scan_c blocks
    const int cI   = (N_I + 255) / 256;

    // ---- pack weights into MFMA fragment order ----
    if (L == 2) {
        pack_all_kernel<<<(184 * 64 + 255) / 256, 256, 0, stream>>>(
            Wp_u, Wp_i, Wl, Wr, Wh, pPu, pPi, pL0, pL1, pH);
    } else {
        pack_w_kernel<<<(4 * 8 * 64 + 255) / 256, 256, 0, stream>>>(Wp_u, 128, 4, 0, 8, 8, pPu);
        pack_w_kernel<<<(2 * 8 * 64 + 255) / 256, 256, 0, stream>>>(Wp_i, 128, 2, 0, 8, 8, pPi);
        for (int l = 0; l < L && l < 2; ++l) {
            ushort* pL = (l == 0) ? pL0 : pL1;
            pack_w_kernel<<<(4 * 8 * 64 + 255) / 256, 256, 0, stream>>>(
                Wl + (size_t)l * H * H, 128, 4, 0, 8, 16, pL);
            pack_w_kernel<<<(4 * 8 * 64 + 255) / 256, 256, 0, stream>>>(
                Wr + (size_t)l * H * H, 128, 4, 8, 8, 16, pL);
        }
        pack_w_kernel<<<(4 * 2 * 64 + 255) / 256, 256, 0, stream>>>(Wh, 32, 4, 0, 2, 2, pH);
    }

    // ---- CSR build (merged U/I per phase) ----
    hipMemsetAsync(degU, 0, (size_t)(N_U + N_I) * sizeof(int), stream);
    count2_kernel<<<(2 * E + 255) / 256, 256, 0, stream>>>(iu_dst, degU, ui_dst, degI, E);
    scan_a2_kernel<<<nbsU + nbsI, 256, 0, stream>>>(degU, N_U, locExU, bsumU, nbsU,
                                                    degI, N_I, locExI, bsumI);
    scan_b2_kernel<<<1, 128, 0, stream>>>(bsumU, nbsU, rowU + N_U, bsumI, nbsI, rowI + N_I);
    scan_c2_kernel<<<cU + cI, 256, 0, stream>>>(locExU, bsumU, N_U, rowU, curU, cU,
                                                locExI, bsumI, N_I, rowI, curI);
    fill2_kernel<<<(2 * E + 255) / 256, 256, 0, stream>>>(iu_src, iu_dst, curU, listsU,
                                                          ui_src, ui_dst, curI, listsI, E);

    // ---- input projections (+bias, relu) -> fp32 h ----
    mfma_gemm2_kernel<128, 8, true, true, false><<<gU, 256, 0, stream>>>(
        x_u, pPu, bp_u, h_u, N_U, gU, x_u, h_u, N_U);
    mfma_gemm2_kernel<64, 8, true, true, false><<<gI, 256, 0, stream>>>(
        x_i, pPi, bp_i, h_i, N_I, gI, x_i, h_i, N_I);

    for (int l = 0; l < L; ++l) {
        const ushort* pL = (l == 0) ? pL0 : pL1;
        // Y = h @ [Wl | Wr] -> bf16  (seg_mean(h)@Wl == seg_mean(h@Wl), linearity)
        mfma_gemm2_kernel<128, 16, false, false, true><<<gU + gI, 256, 0, stream>>>(
            h_u, pL, nullptr, Y_u, N_U, gU, h_i, Y_i, N_I);
        // fused gather-mean + residual + BN + relu, user & item in one dispatch
        gather2_kernel<<<aU + aI, 256, 0, stream>>>(
            Y_i, Y_u, h_u, rowU, listsU,
            bl + l * H, gamma + l * H, beta + l * H, mean + l * H, var + l * H,
            N_U, aU,
            Y_u, Y_i, h_i, rowI, listsI, N_I);
    }

    // ---- head: out0 = h_u @ Wh + bh (h_u already in place as out1) ----
    mfma_gemm2_kernel<128, 2, true, false, false><<<gU, 256, 0, stream>>>(
        h_u, pH, bh, out, N_U, gU, h_u, out, N_U);
}

// Round 7
// 264.447 us; speedup vs baseline: 14.4147x; 1.2390x over previous
//
#include <hip/hip_runtime.h>

constexpr int H = 128;

typedef short bf16x8 __attribute__((ext_vector_type(8)));
typedef float f32x4  __attribute__((ext_vector_type(4)));

__device__ __forceinline__ ushort f2b(float f) {
    uint u = __float_as_uint(f);
    u += 0x7fff + ((u >> 16) & 1);      // round-to-nearest-even
    return (ushort)(u >> 16);
}
__device__ __forceinline__ float b2f(ushort b) {
    return __uint_as_float((uint)b << 16);
}

// ---------------- W pack ----------------
__device__ __forceinline__ void pack_one(const float* __restrict__ W, int ldw,
                                         int t0, int nct, int nctTot,
                                         ushort* __restrict__ dst, int fgl, int l)
{
    int t = fgl % nct, s = fgl / nct;
    int col = t * 16 + (l & 15);
    int kb  = s * 32 + (l >> 4) * 8;
    ushort o[8];
    #pragma unroll
    for (int j = 0; j < 8; ++j) o[j] = f2b(W[(size_t)(kb + j) * ldw + col]);
    ushort* d = dst + ((size_t)(s * nctTot + t0 + t) * 64 + l) * 8;
    *(uint4*)d = *(uint4*)o;
}

__global__ __launch_bounds__(256)
void pack_w_kernel(const float* __restrict__ W, int ldw, int S, int t0, int nct,
                   int nctTot, ushort* __restrict__ dst)
{
    int f = blockIdx.x * 256 + threadIdx.x;
    if (f >= S * nct * 64) return;
    pack_one(W, ldw, t0, nct, nctTot, dst, f >> 6, f & 63);
}

__global__ __launch_bounds__(256)
void pack_all_kernel(const float* __restrict__ Wp_u, const float* __restrict__ Wp_i,
                     const float* __restrict__ Wl, const float* __restrict__ Wr,
                     const float* __restrict__ Wh,
                     ushort* __restrict__ pPu, ushort* __restrict__ pPi,
                     ushort* __restrict__ pL0, ushort* __restrict__ pL1,
                     ushort* __restrict__ pH)
{
    int f = blockIdx.x * 256 + threadIdx.x;
    int fg = f >> 6, l = f & 63;
    if (fg < 32)       pack_one(Wp_u,          128, 0, 8, 8,  pPu, fg,       l);
    else if (fg < 48)  pack_one(Wp_i,          128, 0, 8, 8,  pPi, fg - 32,  l);
    else if (fg < 80)  pack_one(Wl,            128, 0, 8, 16, pL0, fg - 48,  l);
    else if (fg < 112) pack_one(Wr,            128, 8, 8, 16, pL0, fg - 80,  l);
    else if (fg < 144) pack_one(Wl + H * H,    128, 0, 8, 16, pL1, fg - 112, l);
    else if (fg < 176) pack_one(Wr + H * H,    128, 8, 8, 16, pL1, fg - 144, l);
    else if (fg < 184) pack_one(Wh,             32, 0, 2, 2,  pH,  fg - 176, l);
}

// ---------------- MFMA GEMM body + merged-pair kernel ----------------
template<int K, int NCT, bool BIAS, bool RELU, bool OBF16>
__device__ __forceinline__ void mfma_gemm_body(
    const float* __restrict__ A, const ushort* __restrict__ Wp,
    const float* __restrict__ bias, void* __restrict__ Cv, int M, int blk)
{
    constexpr int S   = K / 32;
    constexpr int LDC = NCT * 16;
    const int wave = threadIdx.x >> 6;
    const int lane = threadIdx.x & 63;
    const int row0 = blk * 64 + wave * 16;

    int ar = row0 + (lane & 15);
    if (ar >= M) ar = M - 1;                      // clamp loads; stores guarded
    const float* arow = A + (size_t)ar * K + (lane >> 4) * 8;
    const bf16x8* W8  = (const bf16x8*)Wp;

    f32x4 acc[NCT];
    #pragma unroll
    for (int t = 0; t < NCT; ++t) acc[t] = (f32x4){0.f, 0.f, 0.f, 0.f};

    #pragma unroll
    for (int s = 0; s < S; ++s) {
        float4 f0 = *(const float4*)(arow + s * 32);
        float4 f1 = *(const float4*)(arow + s * 32 + 4);
        bf16x8 a;
        a[0] = (short)f2b(f0.x); a[1] = (short)f2b(f0.y);
        a[2] = (short)f2b(f0.z); a[3] = (short)f2b(f0.w);
        a[4] = (short)f2b(f1.x); a[5] = (short)f2b(f1.y);
        a[6] = (short)f2b(f1.z); a[7] = (short)f2b(f1.w);
        #pragma unroll
        for (int t = 0; t < NCT; ++t) {
            bf16x8 b = W8[(size_t)(s * NCT + t) * 64 + lane];
            acc[t] = __builtin_amdgcn_mfma_f32_16x16x32_bf16(a, b, acc[t], 0, 0, 0);
        }
    }

    const int cg = lane & 15;
    const int rg = (lane >> 4) * 4;
    #pragma unroll
    for (int t = 0; t < NCT; ++t) {
        int col = t * 16 + cg;
        float bb = 0.f;
        if constexpr (BIAS) bb = bias[col];
        #pragma unroll
        for (int r = 0; r < 4; ++r) {
            int row = row0 + rg + r;
            if (row < M) {
                float v = acc[t][r] + bb;
                if constexpr (RELU) v = fmaxf(v, 0.f);
                if constexpr (OBF16)
                    ((ushort*)Cv)[(size_t)row * LDC + col] = f2b(v);
                else
                    ((float*)Cv)[(size_t)row * LDC + col] = v;
            }
        }
    }
}

template<int K, int NCT, bool BIAS, bool RELU, bool OBF16>
__global__ __launch_bounds__(256)
void mfma_gemm2_kernel(const float* __restrict__ A0, const ushort* __restrict__ Wp,
                       const float* __restrict__ bias, void* __restrict__ C0,
                       int M0, int nb0,
                       const float* __restrict__ A1, void* __restrict__ C1, int M1)
{
    if ((int)blockIdx.x < nb0)
        mfma_gemm_body<K, NCT, BIAS, RELU, OBF16>(A0, Wp, bias, C0, M0, blockIdx.x);
    else
        mfma_gemm_body<K, NCT, BIAS, RELU, OBF16>(A1, Wp, bias, C1, M1, blockIdx.x - nb0);
}

// ================= bucketed CSR build (bucket = 256 dst nodes) =================
// B1: per-block LDS histogram of dst>>8 -> global bucket counts
__global__ __launch_bounds__(256)
void bhist_kernel(const int* __restrict__ dstU, int* __restrict__ bCntU,
                  const int* __restrict__ dstI, int* __restrict__ bCntI,
                  int E, int blocksPerSide)
{
    __shared__ int h[256];
    h[threadIdx.x] = 0;
    __syncthreads();
    const int side = blockIdx.x >= blocksPerSide;
    const int* dst = side ? dstI : dstU;
    const int blk  = side ? blockIdx.x - blocksPerSide : blockIdx.x;
    const int i0   = blk * 1024 + threadIdx.x;
    #pragma unroll
    for (int j = 0; j < 4; ++j) {
        int i = i0 + j * 256;
        if (i < E) atomicAdd(&h[dst[i] >> 8], 1);
    }
    __syncthreads();
    int c = h[threadIdx.x];
    if (c) atomicAdd((side ? bCntI : bCntU) + threadIdx.x, c);
}

// B2: exclusive scan of bucket counts for both sides (nbk <= 255 each);
// writes bBase (with sentinel at nbk), copies to bCur, sets rowptr[N] = E.
__global__ __launch_bounds__(512)
void bscan_kernel(const int* __restrict__ bCntU, int nbkU, int* __restrict__ bBaseU,
                  int* __restrict__ bCurU, int* __restrict__ rowUN,
                  const int* __restrict__ bCntI, int nbkI, int* __restrict__ bBaseI,
                  int* __restrict__ bCurI, int* __restrict__ rowIN, int E)
{
    __shared__ int buf[512];
    const int t = threadIdx.x;
    const int half = t >> 8, i = t & 255;
    const int nbk = half ? nbkI : nbkU;
    const int* cnt = half ? bCntI : bCntU;
    int v = (i < nbk) ? cnt[i] : 0;
    buf[t] = v;
    __syncthreads();
    #pragma unroll
    for (int off = 1; off < 256; off <<= 1) {
        int x = (i >= off) ? buf[t - off] : 0;
        __syncthreads();
        buf[t] += x;
        __syncthreads();
    }
    int excl = buf[t] - v;
    int* bBase = half ? bBaseI : bBaseU;
    int* bCur  = half ? bCurI  : bCurU;
    if (i <= nbk) bBase[i] = excl;
    if (i < nbk)  bCur[i]  = excl;
    if (i == 0) *(half ? rowIN : rowUN) = E;
}

// B3: scatter packed (src | dloc<<24) into bucket-contiguous windows.
// Per-block LDS aggregation: one global atomic per (block, bucket).
__global__ __launch_bounds__(256)
void bscatter_kernel(const int* __restrict__ srcU, const int* __restrict__ dstU,
                     int* __restrict__ bCurU, int* __restrict__ pairsU,
                     const int* __restrict__ srcI, const int* __restrict__ dstI,
                     int* __restrict__ bCurI, int* __restrict__ pairsI,
                     int E, int blocksPerSide)
{
    __shared__ int cnt[256];
    __shared__ int basew[256];
    cnt[threadIdx.x] = 0;
    __syncthreads();
    const int side = blockIdx.x >= blocksPerSide;
    const int* src = side ? srcI : srcU;
    const int* dst = side ? dstI : dstU;
    int* bCur  = side ? bCurI  : bCurU;
    int* pairs = side ? pairsI : pairsU;
    const int blk = side ? blockIdx.x - blocksPerSide : blockIdx.x;
    const int i0  = blk * 1024 + threadIdx.x;
    int b[4], lofs[4], pk[4];
    #pragma unroll
    for (int j = 0; j < 4; ++j) {
        int i = i0 + j * 256;
        if (i < E) {
            int d = dst[i];
            b[j] = d >> 8;
            lofs[j] = atomicAdd(&cnt[b[j]], 1);
            pk[j] = src[i] | ((d & 255) << 24);      // src < 2^24 for this problem
        } else b[j] = -1;
    }
    __syncthreads();
    int c = cnt[threadIdx.x];
    if (c) basew[threadIdx.x] = atomicAdd(&bCur[threadIdx.x], c);
    __syncthreads();
    #pragma unroll
    for (int j = 0; j < 4; ++j)
        if (b[j] >= 0) pairs[basew[b[j]] + lofs[j]] = pk[j];
}

// B4: one block per bucket: LDS-stage entries, local count+scan -> rowptr + lists.
__global__ __launch_bounds__(256)
void bfill_kernel(const int* __restrict__ bBaseU, int* __restrict__ rowU,
                  int* __restrict__ listsU, const int* __restrict__ pairsU, int N_U,
                  const int* __restrict__ bBaseI, int* __restrict__ rowI,
                  int* __restrict__ listsI, const int* __restrict__ pairsI, int N_I,
                  int nbkU)
{
    __shared__ int stage[8192];
    __shared__ int cnt[256];
    __shared__ int buf[256];
    __shared__ int cur[256];
    const int t = threadIdx.x;
    const int side = (int)blockIdx.x >= nbkU;
    const int lb = side ? blockIdx.x - nbkU : blockIdx.x;
    const int* bBase = side ? bBaseI : bBaseU;
    const int* pairs = side ? pairsI : pairsU;
    int* rowptr = side ? rowI : rowU;
    int* lists  = side ? listsI : listsU;
    const int N = side ? N_I : N_U;
    const int base = bBase[lb], end = bBase[lb + 1];
    const int n = end - base;
    const bool staged = (n <= 8192);
    cnt[t] = 0;
    __syncthreads();
    for (int k = t; k < n; k += 256) {
        int v = pairs[base + k];
        if (staged) stage[k] = v;
        atomicAdd(&cnt[(v >> 24) & 255], 1);
    }
    __syncthreads();
    int val = cnt[t];
    buf[t] = val;
    __syncthreads();
    #pragma unroll
    for (int off = 1; off < 256; off <<= 1) {
        int x = (t >= off) ? buf[t - off] : 0;
        __syncthreads();
        buf[t] += x;
        __syncthreads();
    }
    int excl = buf[t] - val;
    int node = lb * 256 + t;
    if (node < N) rowptr[node] = base + excl;
    cur[t] = excl;
    __syncthreads();
    for (int k = t; k < n; k += 256) {
        int v = staged ? stage[k] : pairs[base + k];
        int dl = (v >> 24) & 255;
        int pos = base + atomicAdd(&cur[dl], 1);
        lists[pos] = v & 0xFFFFFF;
    }
}

// ---------------- fused gather + SAGE update (Y bf16, edge-parallel) --------
template<bool BN>
__device__ __forceinline__ void gather_body(
    const ushort* __restrict__ Ysrc, const ushort* __restrict__ Ydst,
    float* __restrict__ h,
    const int* __restrict__ rowptr, const int* __restrict__ lists,
    const float* __restrict__ bl, const float* __restrict__ gamma,
    const float* __restrict__ beta, const float* __restrict__ mean,
    const float* __restrict__ var, int N, int blk)
{
    const int node = blk * 4 + (threadIdx.x >> 6);
    if (node >= N) return;
    const int lane = threadIdx.x & 63;
    const int grp  = lane >> 4;
    const int c8   = (lane & 15) * 8;

    const int beg = rowptr[node];
    const int end = rowptr[node + 1];

    float s[8] = {0.f, 0.f, 0.f, 0.f, 0.f, 0.f, 0.f, 0.f};
    int e = beg + grp;
    for (; e + 4 < end; e += 8) {                 // 8 edges in flight per wave
        int s0 = lists[e], s1 = lists[e + 4];
        uint4 v0 = *(const uint4*)&Ysrc[(size_t)s0 * 2 * H + c8];
        uint4 v1 = *(const uint4*)&Ysrc[(size_t)s1 * 2 * H + c8];
        s[0] += b2f((ushort)v0.x) + b2f((ushort)v1.x);
        s[1] += b2f((ushort)(v0.x >> 16)) + b2f((ushort)(v1.x >> 16));
        s[2] += b2f((ushort)v0.y) + b2f((ushort)v1.y);
        s[3] += b2f((ushort)(v0.y >> 16)) + b2f((ushort)(v1.y >> 16));
        s[4] += b2f((ushort)v0.z) + b2f((ushort)v1.z);
        s[5] += b2f((ushort)(v0.z >> 16)) + b2f((ushort)(v1.z >> 16));
        s[6] += b2f((ushort)v0.w) + b2f((ushort)v1.w);
        s[7] += b2f((ushort)(v0.w >> 16)) + b2f((ushort)(v1.w >> 16));
    }
    if (e < end) {
        int s0 = lists[e];
        uint4 v0 = *(const uint4*)&Ysrc[(size_t)s0 * 2 * H + c8];
        s[0] += b2f((ushort)v0.x); s[1] += b2f((ushort)(v0.x >> 16));
        s[2] += b2f((ushort)v0.y); s[3] += b2f((ushort)(v0.y >> 16));
        s[4] += b2f((ushort)v0.z); s[5] += b2f((ushort)(v0.z >> 16));
        s[6] += b2f((ushort)v0.w); s[7] += b2f((ushort)(v0.w >> 16));
    }
    #pragma unroll
    for (int j = 0; j < 8; ++j) {
        s[j] += __shfl_xor(s[j], 16, 64);
        s[j] += __shfl_xor(s[j], 32, 64);
    }
    if (grp != 0) return;                          // lanes 0-15 finish the node
    const int deg = end - beg;
    const float sc = (deg > 0) ? 1.0f / (float)deg : 0.f;

    uint4 yv = *(const uint4*)&Ydst[(size_t)node * 2 * H + H + c8];
    float y[8] = { b2f((ushort)yv.x), b2f((ushort)(yv.x >> 16)),
                   b2f((ushort)yv.y), b2f((ushort)(yv.y >> 16)),
                   b2f((ushort)yv.z), b2f((ushort)(yv.z >> 16)),
                   b2f((ushort)yv.w), b2f((ushort)(yv.w >> 16)) };
    float4 h0 = *(const float4*)&h[(size_t)node * H + c8];
    float4 h1 = *(const float4*)&h[(size_t)node * H + c8 + 4];
    float hh[8] = {h0.x, h0.y, h0.z, h0.w, h1.x, h1.y, h1.z, h1.w};
    float o[8];
    #pragma unroll
    for (int j = 0; j < 8; ++j) {
        float u = (hh[j] + s[j] * sc + y[j] + bl[c8 + j]) * 0.5f;
        if constexpr (BN)
            u = (u - mean[c8 + j]) * rsqrtf(var[c8 + j] + 1e-5f) * gamma[c8 + j] + beta[c8 + j];
        o[j] = fmaxf(u, 0.f);
    }
    *(float4*)&h[(size_t)node * H + c8]     = make_float4(o[0], o[1], o[2], o[3]);
    *(float4*)&h[(size_t)node * H + c8 + 4] = make_float4(o[4], o[5], o[6], o[7]);
}

__global__ __launch_bounds__(256)
void gather2_kernel(const ushort* __restrict__ Ys0, const ushort* __restrict__ Yd0,
                    float* __restrict__ h0,
                    const int* __restrict__ rp0, const int* __restrict__ li0,
                    const float* __restrict__ bl, const float* __restrict__ gamma,
                    const float* __restrict__ beta, const float* __restrict__ mean,
                    const float* __restrict__ var, int N0, int nb0,
                    const ushort* __restrict__ Ys1, const ushort* __restrict__ Yd1,
                    float* __restrict__ h1,
                    const int* __restrict__ rp1, const int* __restrict__ li1, int N1)
{
    if ((int)blockIdx.x < nb0)
        gather_body<true>(Ys0, Yd0, h0, rp0, li0, bl, gamma, beta, mean, var, N0, blockIdx.x);
    else
        gather_body<false>(Ys1, Yd1, h1, rp1, li1, bl, gamma, beta, mean, var, N1,
                           blockIdx.x - nb0);
}

extern "C" void kernel_launch(void* const* d_in, const int* in_sizes, int n_in,
                              void* d_out, int out_size, void* d_ws, size_t ws_size,
                              hipStream_t stream)
{
    const float* x_u   = (const float*)d_in[0];
    const float* x_i   = (const float*)d_in[1];
    const int*   iu_src = (const int*)d_in[2];
    const int*   iu_dst = (const int*)d_in[3];
    const int*   ui_src = (const int*)d_in[4];
    const int*   ui_dst = (const int*)d_in[5];
    const float* Wp_u  = (const float*)d_in[6];
    const float* bp_u  = (const float*)d_in[7];
    const float* Wp_i  = (const float*)d_in[8];
    const float* bp_i  = (const float*)d_in[9];
    const float* Wl    = (const float*)d_in[10];
    const float* bl    = (const float*)d_in[11];
    const float* Wr    = (const float*)d_in[12];
    const float* gamma = (const float*)d_in[13];
    const float* beta  = (const float*)d_in[14];
    const float* mean  = (const float*)d_in[15];
    const float* var   = (const float*)d_in[16];
    const float* Wh    = (const float*)d_in[17];
    const float* bh    = (const float*)d_in[18];

    const int N_U = in_sizes[0] / 128;      // 50000
    const int N_I = in_sizes[1] / 64;       // 30000
    const int E   = in_sizes[2];            // 500000
    const int L   = in_sizes[10] / (H * H); // 2
    const int OUT = 32;

    float* out = (float*)d_out;
    float* h_u = out + (size_t)N_U * OUT;   // h_u lives in its output slot

    // workspace layout
    float*  ws   = (float*)d_ws;
    float*  h_i  = ws;                                // [N_I,128] fp32
    ushort* Y_u  = (ushort*)(h_i + (size_t)N_I * H);  // [N_U,256] bf16
    ushort* Y_i  = Y_u + (size_t)N_U * 2 * H;         // [N_I,256] bf16
    int*    ip   = (int*)(((uintptr_t)(Y_i + (size_t)N_I * 2 * H) + 15) & ~(uintptr_t)15);
    int* rowU    = ip;               ip += N_U + 1;
    int* rowI    = ip;               ip += N_I + 1;
    int* listsU  = ip;               ip += E;
    int* listsI  = ip;               ip += E;
    int* pairsU  = ip;               ip += E;
    int* pairsI  = ip;               ip += E;
    int* bCntU   = ip;               ip += 256;
    int* bCntI   = ip;               ip += 256;
    int* bBaseU  = ip;               ip += 260;
    int* bBaseI  = ip;               ip += 260;
    int* bCurU   = ip;               ip += 256;
    int* bCurI   = ip;               ip += 256;
    // packed weights (bf16), 16B-aligned
    ushort* up   = (ushort*)(((uintptr_t)ip + 15) & ~(uintptr_t)15);
    ushort* pPu  = up;               up += 4 * 8  * 64 * 8;   // K=128, NCT=8
    ushort* pPi  = up;               up += 2 * 8  * 64 * 8;   // K=64,  NCT=8
    ushort* pL0  = up;               up += 4 * 16 * 64 * 8;   // K=128, NCT=16
    ushort* pL1  = up;               up += 4 * 16 * 64 * 8;
    ushort* pH   = up;               up += 4 * 2  * 64 * 8;   // K=128, NCT=2

    const int nbkU = (N_U + 255) / 256;     // buckets (<= 255 each)
    const int nbkI = (N_I + 255) / 256;
    const int ebs  = (E + 1023) / 1024;     // edge blocks per side
    const int gU   = (N_U + 63) / 64;       // gemm blocks
    const int gI   = (N_I + 63) / 64;
    const int aU   = (N_U + 3) / 4;         // gather blocks
    const int aI   = (N_I + 3) / 4;

    // ---- pack weights into MFMA fragment order ----
    if (L == 2) {
        pack_all_kernel<<<(184 * 64 + 255) / 256, 256, 0, stream>>>(
            Wp_u, Wp_i, Wl, Wr, Wh, pPu, pPi, pL0, pL1, pH);
    } else {
        pack_w_kernel<<<(4 * 8 * 64 + 255) / 256, 256, 0, stream>>>(Wp_u, 128, 4, 0, 8, 8, pPu);
        pack_w_kernel<<<(2 * 8 * 64 + 255) / 256, 256, 0, stream>>>(Wp_i, 128, 2, 0, 8, 8, pPi);
        for (int l = 0; l < L && l < 2; ++l) {
            ushort* pL = (l == 0) ? pL0 : pL1;
            pack_w_kernel<<<(4 * 8 * 64 + 255) / 256, 256, 0, stream>>>(
                Wl + (size_t)l * H * H, 128, 4, 0, 8, 16, pL);
            pack_w_kernel<<<(4 * 8 * 64 + 255) / 256, 256, 0, stream>>>(
                Wr + (size_t)l * H * H, 128, 4, 8, 8, 16, pL);
        }
        pack_w_kernel<<<(4 * 2 * 64 + 255) / 256, 256, 0, stream>>>(Wh, 32, 4, 0, 2, 2, pH);
    }

    // ---- bucketed CSR build ----
    hipMemsetAsync(bCntU, 0, 512 * sizeof(int), stream);   // bCntU + bCntI contiguous
    bhist_kernel<<<2 * ebs, 256, 0, stream>>>(iu_dst, bCntU, ui_dst, bCntI, E, ebs);
    bscan_kernel<<<1, 512, 0, stream>>>(bCntU, nbkU, bBaseU, bCurU, rowU + N_U,
                                        bCntI, nbkI, bBaseI, bCurI, rowI + N_I, E);
    bscatter_kernel<<<2 * ebs, 256, 0, stream>>>(iu_src, iu_dst, bCurU, pairsU,
                                                 ui_src, ui_dst, bCurI, pairsI, E, ebs);
    bfill_kernel<<<nbkU + nbkI, 256, 0, stream>>>(bBaseU, rowU, listsU, pairsU, N_U,
                                                  bBaseI, rowI, listsI, pairsI, N_I, nbkU);

    // ---- input projections (+bias, relu) -> fp32 h ----
    mfma_gemm2_kernel<128, 8, true, true, false><<<gU, 256, 0, stream>>>(
        x_u, pPu, bp_u, h_u, N_U, gU, x_u, h_u, N_U);
    mfma_gemm2_kernel<64, 8, true, true, false><<<gI, 256, 0, stream>>>(
        x_i, pPi, bp_i, h_i, N_I, gI, x_i, h_i, N_I);

    for (int l = 0; l < L; ++l) {
        const ushort* pL = (l == 0) ? pL0 : pL1;
        // Y = h @ [Wl | Wr] -> bf16  (seg_mean(h)@Wl == seg_mean(h@Wl), linearity)
        mfma_gemm2_kernel<128, 16, false, false, true><<<gU + gI, 256, 0, stream>>>(
            h_u, pL, nullptr, Y_u, N_U, gU, h_i, Y_i, N_I);
        // fused gather-mean + residual + BN + relu, user & item in one dispatch
        gather2_kernel<<<aU + aI, 256, 0, stream>>>(
            Y_i, Y_u, h_u, rowU, listsU,
            bl + l * H, gamma + l * H, beta + l * H, mean + l * H, var + l * H,
            N_U, aU,
            Y_u, Y_i, h_i, rowI, listsI, N_I);
    }

    // ---- head: out0 = h_u @ Wh + bh (h_u already in place as out1) ----
    mfma_gemm2_kernel<128, 2, true, false, false><<<gU, 256, 0, stream>>>(
        h_u, pH, bh, out, N_U, gU, h_u, out, N_U);
}

// Round 8
// 242.952 us; speedup vs baseline: 15.6900x; 1.0885x over previous
//
#include <hip/hip_runtime.h>

constexpr int H = 128;

typedef short bf16x8 __attribute__((ext_vector_type(8)));
typedef float f32x4  __attribute__((ext_vector_type(4)));

__device__ __forceinline__ ushort f2b(float f) {
    uint u = __float_as_uint(f);
    u += 0x7fff + ((u >> 16) & 1);      // round-to-nearest-even
    return (ushort)(u >> 16);
}
__device__ __forceinline__ float b2f(ushort b) {
    return __uint_as_float((uint)b << 16);
}

// ---------------- W pack: frag[s][t0+t][lane][j] = W'[s*32+8*(l/16)+j][t*16+l%16]
// addI != 0 folds +identity into the packed matrix (Wr' = Wr + I).
__device__ __forceinline__ void pack_one(const float* __restrict__ W, int ldw,
                                         int t0, int nct, int nctTot,
                                         ushort* __restrict__ dst, int fgl, int l,
                                         float addI)
{
    int t = fgl % nct, s = fgl / nct;
    int col = t * 16 + (l & 15);
    int kb  = s * 32 + (l >> 4) * 8;
    ushort o[8];
    #pragma unroll
    for (int j = 0; j < 8; ++j) {
        float v = W[(size_t)(kb + j) * ldw + col];
        if (kb + j == col) v += addI;
        o[j] = f2b(v);
    }
    ushort* d = dst + ((size_t)(s * nctTot + t0 + t) * 64 + l) * 8;
    *(uint4*)d = *(uint4*)o;
}

__global__ __launch_bounds__(256)
void pack_all_kernel(const float* __restrict__ Wp_u, const float* __restrict__ Wp_i,
                     const float* __restrict__ Wl, const float* __restrict__ Wr,
                     const float* __restrict__ Wh,
                     ushort* __restrict__ pPu, ushort* __restrict__ pPi,
                     ushort* __restrict__ pL0, ushort* __restrict__ pL1,
                     ushort* __restrict__ pH)
{
    int f = blockIdx.x * 256 + threadIdx.x;
    int fg = f >> 6, l = f & 63;
    if (fg < 32)       pack_one(Wp_u,          128, 0, 8, 8,  pPu, fg,       l, 0.f);
    else if (fg < 48)  pack_one(Wp_i,          128, 0, 8, 8,  pPi, fg - 32,  l, 0.f);
    else if (fg < 80)  pack_one(Wl,            128, 0, 8, 16, pL0, fg - 48,  l, 0.f);
    else if (fg < 112) pack_one(Wr,            128, 8, 8, 16, pL0, fg - 80,  l, 1.f);
    else if (fg < 144) pack_one(Wl + H * H,    128, 0, 8, 16, pL1, fg - 112, l, 0.f);
    else if (fg < 176) pack_one(Wr + H * H,    128, 8, 8, 16, pL1, fg - 144, l, 1.f);
    else if (fg < 184) pack_one(Wh,             32, 0, 2, 2,  pH,  fg - 176, l, 0.f);
}

// ---------------- MFMA GEMM body (A fp32 or bf16; C fp32 or bf16) ----------
template<int K, int NCT, bool ABF16, bool BIAS, bool RELU, bool OBF16>
__device__ __forceinline__ void mfma_gemm_body(
    const void* __restrict__ Av, const ushort* __restrict__ Wp,
    const float* __restrict__ bias, void* __restrict__ Cv, int M, int blk)
{
    constexpr int S   = K / 32;
    constexpr int LDC = NCT * 16;
    const int wave = threadIdx.x >> 6;
    const int lane = threadIdx.x & 63;
    const int row0 = blk * 64 + wave * 16;

    int ar = row0 + (lane & 15);
    if (ar >= M) ar = M - 1;                      // clamp loads; stores guarded
    const bf16x8* W8 = (const bf16x8*)Wp;

    f32x4 acc[NCT];
    #pragma unroll
    for (int t = 0; t < NCT; ++t) acc[t] = (f32x4){0.f, 0.f, 0.f, 0.f};

    #pragma unroll
    for (int s = 0; s < S; ++s) {
        bf16x8 a;
        if constexpr (ABF16) {
            const ushort* arow = (const ushort*)Av + (size_t)ar * K + (lane >> 4) * 8;
            a = *(const bf16x8*)(arow + s * 32);
        } else {
            const float* arow = (const float*)Av + (size_t)ar * K + (lane >> 4) * 8;
            float4 f0 = *(const float4*)(arow + s * 32);
            float4 f1 = *(const float4*)(arow + s * 32 + 4);
            a[0] = (short)f2b(f0.x); a[1] = (short)f2b(f0.y);
            a[2] = (short)f2b(f0.z); a[3] = (short)f2b(f0.w);
            a[4] = (short)f2b(f1.x); a[5] = (short)f2b(f1.y);
            a[6] = (short)f2b(f1.z); a[7] = (short)f2b(f1.w);
        }
        #pragma unroll
        for (int t = 0; t < NCT; ++t) {
            bf16x8 b = W8[(size_t)(s * NCT + t) * 64 + lane];
            acc[t] = __builtin_amdgcn_mfma_f32_16x16x32_bf16(a, b, acc[t], 0, 0, 0);
        }
    }

    const int cg = lane & 15;
    const int rg = (lane >> 4) * 4;
    #pragma unroll
    for (int t = 0; t < NCT; ++t) {
        int col = t * 16 + cg;
        float bb = 0.f;
        if constexpr (BIAS) bb = bias[col];
        #pragma unroll
        for (int r = 0; r < 4; ++r) {
            int row = row0 + rg + r;
            if (row < M) {
                float v = acc[t][r] + bb;
                if constexpr (RELU) v = fmaxf(v, 0.f);
                if constexpr (OBF16)
                    ((ushort*)Cv)[(size_t)row * LDC + col] = f2b(v);
                else
                    ((float*)Cv)[(size_t)row * LDC + col] = v;
            }
        }
    }
}

// merged layer GEMM (both sides, bf16 A, bf16 out)
__global__ __launch_bounds__(256)
void gemm_layer2_kernel(const ushort* __restrict__ A0, const ushort* __restrict__ Wp,
                        ushort* __restrict__ C0, int M0, int nb0,
                        const ushort* __restrict__ A1, ushort* __restrict__ C1, int M1)
{
    if ((int)blockIdx.x < nb0)
        mfma_gemm_body<128, 16, true, false, false, true>(A0, Wp, nullptr, C0, M0, blockIdx.x);
    else
        mfma_gemm_body<128, 16, true, false, false, true>(A1, Wp, nullptr, C1, M1,
                                                          blockIdx.x - nb0);
}

// merged projections (fp32 A, bf16 out, bias+relu); U side K=128, I side K=64
__global__ __launch_bounds__(256)
void proj2_kernel(const float* __restrict__ x_u, const ushort* __restrict__ pPu,
                  const float* __restrict__ bp_u, ushort* __restrict__ hU,
                  int N_U, int nb0,
                  const float* __restrict__ x_i, const ushort* __restrict__ pPi,
                  const float* __restrict__ bp_i, ushort* __restrict__ hI, int N_I)
{
    if ((int)blockIdx.x < nb0)
        mfma_gemm_body<128, 8, false, true, true, true>(x_u, pPu, bp_u, hU, N_U, blockIdx.x);
    else
        mfma_gemm_body<64, 8, false, true, true, true>(x_i, pPi, bp_i, hI, N_I,
                                                       blockIdx.x - nb0);
}

// head: out0 = hU(bf16) @ Wh + bh -> fp32
__global__ __launch_bounds__(256)
void head_kernel(const ushort* __restrict__ A, const ushort* __restrict__ Wp,
                 const float* __restrict__ bias, float* __restrict__ C, int M)
{
    mfma_gemm_body<128, 2, true, true, false, false>(A, Wp, bias, C, M, blockIdx.x);
}

// ================= bucketed CSR build (bucket = 256 dst nodes) =================
__global__ __launch_bounds__(256)
void bhist_kernel(const int* __restrict__ dstU, int* __restrict__ bCntU,
                  const int* __restrict__ dstI, int* __restrict__ bCntI,
                  int E, int blocksPerSide)
{
    __shared__ int h[256];
    h[threadIdx.x] = 0;
    __syncthreads();
    const int side = blockIdx.x >= blocksPerSide;
    const int* dst = side ? dstI : dstU;
    const int blk  = side ? blockIdx.x - blocksPerSide : blockIdx.x;
    const int i0   = blk * 1024 + threadIdx.x;
    #pragma unroll
    for (int j = 0; j < 4; ++j) {
        int i = i0 + j * 256;
        if (i < E) atomicAdd(&h[dst[i] >> 8], 1);
    }
    __syncthreads();
    int c = h[threadIdx.x];
    if (c) atomicAdd((side ? bCntI : bCntU) + threadIdx.x, c);
}

__global__ __launch_bounds__(512)
void bscan_kernel(const int* __restrict__ bCntU, int nbkU, int* __restrict__ bBaseU,
                  int* __restrict__ bCurU, int* __restrict__ rowUN,
                  const int* __restrict__ bCntI, int nbkI, int* __restrict__ bBaseI,
                  int* __restrict__ bCurI, int* __restrict__ rowIN, int E)
{
    __shared__ int buf[512];
    const int t = threadIdx.x;
    const int half = t >> 8, i = t & 255;
    const int nbk = half ? nbkI : nbkU;
    const int* cnt = half ? bCntI : bCntU;
    int v = (i < nbk) ? cnt[i] : 0;
    buf[t] = v;
    __syncthreads();
    #pragma unroll
    for (int off = 1; off < 256; off <<= 1) {
        int x = (i >= off) ? buf[t - off] : 0;
        __syncthreads();
        buf[t] += x;
        __syncthreads();
    }
    int excl = buf[t] - v;
    int* bBase = half ? bBaseI : bBaseU;
    int* bCur  = half ? bCurI  : bCurU;
    if (i <= nbk) bBase[i] = excl;
    if (i < nbk)  bCur[i]  = excl;
    if (i == 0) *(half ? rowIN : rowUN) = E;
}

__global__ __launch_bounds__(256)
void bscatter_kernel(const int* __restrict__ srcU, const int* __restrict__ dstU,
                     int* __restrict__ bCurU, int* __restrict__ pairsU,
                     const int* __restrict__ srcI, const int* __restrict__ dstI,
                     int* __restrict__ bCurI, int* __restrict__ pairsI,
                     int E, int blocksPerSide)
{
    __shared__ int cnt[256];
    __shared__ int basew[256];
    cnt[threadIdx.x] = 0;
    __syncthreads();
    const int side = blockIdx.x >= blocksPerSide;
    const int* src = side ? srcI : srcU;
    const int* dst = side ? dstI : dstU;
    int* bCur  = side ? bCurI  : bCurU;
    int* pairs = side ? pairsI : pairsU;
    const int blk = side ? blockIdx.x - blocksPerSide : blockIdx.x;
    const int i0  = blk * 1024 + threadIdx.x;
    int b[4], lofs[4], pk[4];
    #pragma unroll
    for (int j = 0; j < 4; ++j) {
        int i = i0 + j * 256;
        if (i < E) {
            int d = dst[i];
            b[j] = d >> 8;
            lofs[j] = atomicAdd(&cnt[b[j]], 1);
            pk[j] = src[i] | ((d & 255) << 24);      // src < 2^24 for this problem
        } else b[j] = -1;
    }
    __syncthreads();
    int c = cnt[threadIdx.x];
    if (c) basew[threadIdx.x] = atomicAdd(&bCur[threadIdx.x], c);
    __syncthreads();
    #pragma unroll
    for (int j = 0; j < 4; ++j)
        if (b[j] >= 0) pairs[basew[b[j]] + lofs[j]] = pk[j];
}

__global__ __launch_bounds__(256)
void bfill_kernel(const int* __restrict__ bBaseU, int* __restrict__ rowU,
                  int* __restrict__ listsU, const int* __restrict__ pairsU, int N_U,
                  const int* __restrict__ bBaseI, int* __restrict__ rowI,
                  int* __restrict__ listsI, const int* __restrict__ pairsI, int N_I,
                  int nbkU)
{
    __shared__ int stage[8192];
    __shared__ int cnt[256];
    __shared__ int buf[256];
    __shared__ int cur[256];
    const int t = threadIdx.x;
    const int side = (int)blockIdx.x >= nbkU;
    const int lb = side ? blockIdx.x - nbkU : blockIdx.x;
    const int* bBase = side ? bBaseI : bBaseU;
    const int* pairs = side ? pairsI : pairsU;
    int* rowptr = side ? rowI : rowU;
    int* lists  = side ? listsI : listsU;
    const int N = side ? N_I : N_U;
    const int base = bBase[lb], end = bBase[lb + 1];
    const int n = end - base;
    const bool staged = (n <= 8192);
    cnt[t] = 0;
    __syncthreads();
    for (int k = t; k < n; k += 256) {
        int v = pairs[base + k];
        if (staged) stage[k] = v;
        atomicAdd(&cnt[(v >> 24) & 255], 1);
    }
    __syncthreads();
    int val = cnt[t];
    buf[t] = val;
    __syncthreads();
    #pragma unroll
    for (int off = 1; off < 256; off <<= 1) {
        int x = (t >= off) ? buf[t - off] : 0;
        __syncthreads();
        buf[t] += x;
        __syncthreads();
    }
    int excl = buf[t] - val;
    int node = lb * 256 + t;
    if (node < N) rowptr[node] = base + excl;
    cur[t] = excl;
    __syncthreads();
    for (int k = t; k < n; k += 256) {
        int v = staged ? stage[k] : pairs[base + k];
        int dl = (v >> 24) & 255;
        int pos = base + atomicAdd(&cur[dl], 1);
        lists[pos] = v & 0xFFFFFF;
    }
}

// ---------------- fused gather + SAGE update --------------------------------
// u = (agg@Wl + h@(Wr+I) + bl) * 0.5 ; [BN] ; relu -> h (bf16) [+ fp32 out1]
template<bool BN>
__device__ __forceinline__ void gather_body(
    const ushort* __restrict__ Ysrc, const ushort* __restrict__ Ydst,
    ushort* __restrict__ hB, float* __restrict__ out1,
    const int* __restrict__ rowptr, const int* __restrict__ lists,
    const float* __restrict__ bl, const float* __restrict__ gamma,
    const float* __restrict__ beta, const float* __restrict__ mean,
    const float* __restrict__ var, int N, int blk)
{
    const int node = blk * 4 + (threadIdx.x >> 6);
    if (node >= N) return;
    const int lane = threadIdx.x & 63;
    const int grp  = lane >> 4;
    const int c8   = (lane & 15) * 8;

    const int beg = rowptr[node];
    const int end = rowptr[node + 1];

    float s[8] = {0.f, 0.f, 0.f, 0.f, 0.f, 0.f, 0.f, 0.f};
    int e = beg + grp;
    for (; e + 4 < end; e += 8) {                 // 8 edges in flight per wave
        int s0 = lists[e], s1 = lists[e + 4];
        uint4 v0 = *(const uint4*)&Ysrc[(size_t)s0 * 2 * H + c8];
        uint4 v1 = *(const uint4*)&Ysrc[(size_t)s1 * 2 * H + c8];
        s[0] += b2f((ushort)v0.x) + b2f((ushort)v1.x);
        s[1] += b2f((ushort)(v0.x >> 16)) + b2f((ushort)(v1.x >> 16));
        s[2] += b2f((ushort)v0.y) + b2f((ushort)v1.y);
        s[3] += b2f((ushort)(v0.y >> 16)) + b2f((ushort)(v1.y >> 16));
        s[4] += b2f((ushort)v0.z) + b2f((ushort)v1.z);
        s[5] += b2f((ushort)(v0.z >> 16)) + b2f((ushort)(v1.z >> 16));
        s[6] += b2f((ushort)v0.w) + b2f((ushort)v1.w);
        s[7] += b2f((ushort)(v0.w >> 16)) + b2f((ushort)(v1.w >> 16));
    }
    if (e < end) {
        int s0 = lists[e];
        uint4 v0 = *(const uint4*)&Ysrc[(size_t)s0 * 2 * H + c8];
        s[0] += b2f((ushort)v0.x); s[1] += b2f((ushort)(v0.x >> 16));
        s[2] += b2f((ushort)v0.y); s[3] += b2f((ushort)(v0.y >> 16));
        s[4] += b2f((ushort)v0.z); s[5] += b2f((ushort)(v0.z >> 16));
        s[6] += b2f((ushort)v0.w); s[7] += b2f((ushort)(v0.w >> 16));
    }
    #pragma unroll
    for (int j = 0; j < 8; ++j) {
        s[j] += __shfl_xor(s[j], 16, 64);
        s[j] += __shfl_xor(s[j], 32, 64);
    }
    if (grp != 0) return;                          // lanes 0-15 finish the node
    const int deg = end - beg;
    const float sc = (deg > 0) ? 1.0f / (float)deg : 0.f;

    uint4 yv = *(const uint4*)&Ydst[(size_t)node * 2 * H + H + c8];
    float y[8] = { b2f((ushort)yv.x), b2f((ushort)(yv.x >> 16)),
                   b2f((ushort)yv.y), b2f((ushort)(yv.y >> 16)),
                   b2f((ushort)yv.z), b2f((ushort)(yv.z >> 16)),
                   b2f((ushort)yv.w), b2f((ushort)(yv.w >> 16)) };
    float o[8];
    #pragma unroll
    for (int j = 0; j < 8; ++j) {
        float u = (s[j] * sc + y[j] + bl[c8 + j]) * 0.5f;
        if constexpr (BN)
            u = (u - mean[c8 + j]) * rsqrtf(var[c8 + j] + 1e-5f) * gamma[c8 + j] + beta[c8 + j];
        o[j] = fmaxf(u, 0.f);
    }
    ushort hb[8];
    #pragma unroll
    for (int j = 0; j < 8; ++j) hb[j] = f2b(o[j]);
    *(uint4*)&hB[(size_t)node * H + c8] = *(uint4*)hb;
    if (out1) {
        *(float4*)&out1[(size_t)node * H + c8]     = make_float4(o[0], o[1], o[2], o[3]);
        *(float4*)&out1[(size_t)node * H + c8 + 4] = make_float4(o[4], o[5], o[6], o[7]);
    }
}

__global__ __launch_bounds__(256)
void gather2_kernel(const ushort* __restrict__ Ys0, const ushort* __restrict__ Yd0,
                    ushort* __restrict__ hB0, float* __restrict__ out1,
                    const int* __restrict__ rp0, const int* __restrict__ li0,
                    const float* __restrict__ bl, const float* __restrict__ gamma,
                    const float* __restrict__ beta, const float* __restrict__ mean,
                    const float* __restrict__ var, int N0, int nb0,
                    const ushort* __restrict__ Ys1, const ushort* __restrict__ Yd1,
                    ushort* __restrict__ hB1,
                    const int* __restrict__ rp1, const int* __restrict__ li1, int N1)
{
    if ((int)blockIdx.x < nb0)
        gather_body<true>(Ys0, Yd0, hB0, out1, rp0, li0, bl, gamma, beta, mean, var,
                          N0, blockIdx.x);
    else
        gather_body<false>(Ys1, Yd1, hB1, nullptr, rp1, li1, bl, gamma, beta, mean, var,
                           N1, blockIdx.x - nb0);
}

extern "C" void kernel_launch(void* const* d_in, const int* in_sizes, int n_in,
                              void* d_out, int out_size, void* d_ws, size_t ws_size,
                              hipStream_t stream)
{
    const float* x_u   = (const float*)d_in[0];
    const float* x_i   = (const float*)d_in[1];
    const int*   iu_src = (const int*)d_in[2];
    const int*   iu_dst = (const int*)d_in[3];
    const int*   ui_src = (const int*)d_in[4];
    const int*   ui_dst = (const int*)d_in[5];
    const float* Wp_u  = (const float*)d_in[6];
    const float* bp_u  = (const float*)d_in[7];
    const float* Wp_i  = (const float*)d_in[8];
    const float* bp_i  = (const float*)d_in[9];
    const float* Wl    = (const float*)d_in[10];
    const float* bl    = (const float*)d_in[11];
    const float* Wr    = (const float*)d_in[12];
    const float* gamma = (const float*)d_in[13];
    const float* beta  = (const float*)d_in[14];
    const float* mean  = (const float*)d_in[15];
    const float* var   = (const float*)d_in[16];
    const float* Wh    = (const float*)d_in[17];
    const float* bh    = (const float*)d_in[18];

    const int N_U = in_sizes[0] / 128;      // 50000
    const int N_I = in_sizes[1] / 64;       // 30000
    const int E   = in_sizes[2];            // 500000
    const int L   = in_sizes[10] / (H * H); // 2 (this path assumes 2)
    const int OUT = 32;

    float* out  = (float*)d_out;
    float* out1 = out + (size_t)N_U * OUT;

    // workspace layout
    ushort* hU   = (ushort*)d_ws;                     // [N_U,128] bf16
    ushort* hI   = hU + (size_t)N_U * H;              // [N_I,128] bf16
    ushort* Y_u  = hI + (size_t)N_I * H;              // [N_U,256] bf16
    ushort* Y_i  = Y_u + (size_t)N_U * 2 * H;         // [N_I,256] bf16
    int*    ip   = (int*)(((uintptr_t)(Y_i + (size_t)N_I * 2 * H) + 15) & ~(uintptr_t)15);
    int* rowU    = ip;               ip += N_U + 1;
    int* rowI    = ip;               ip += N_I + 1;
    int* listsU  = ip;               ip += E;
    int* listsI  = ip;               ip += E;
    int* pairsU  = ip;               ip += E;
    int* pairsI  = ip;               ip += E;
    int* bCntU   = ip;               ip += 256;
    int* bCntI   = ip;               ip += 256;
    int* bBaseU  = ip;               ip += 260;
    int* bBaseI  = ip;               ip += 260;
    int* bCurU   = ip;               ip += 256;
    int* bCurI   = ip;               ip += 256;
    // packed weights (bf16), 16B-aligned
    ushort* up   = (ushort*)(((uintptr_t)ip + 15) & ~(uintptr_t)15);
    ushort* pPu  = up;               up += 4 * 8  * 64 * 8;   // K=128, NCT=8
    ushort* pPi  = up;               up += 2 * 8  * 64 * 8;   // K=64,  NCT=8
    ushort* pL0  = up;               up += 4 * 16 * 64 * 8;   // K=128, NCT=16
    ushort* pL1  = up;               up += 4 * 16 * 64 * 8;
    ushort* pH   = up;               up += 4 * 2  * 64 * 8;   // K=128, NCT=2

    const int nbkU = (N_U + 255) / 256;     // buckets (<= 255 each)
    const int nbkI = (N_I + 255) / 256;
    const int ebs  = (E + 1023) / 1024;     // edge blocks per side
    const int gU   = (N_U + 63) / 64;       // gemm blocks
    const int gI   = (N_I + 63) / 64;
    const int aU   = (N_U + 3) / 4;         // gather blocks
    const int aI   = (N_I + 3) / 4;

    // ---- pack weights (Wr halves get +I folded in) ----
    pack_all_kernel<<<(184 * 64 + 255) / 256, 256, 0, stream>>>(
        Wp_u, Wp_i, Wl, Wr, Wh, pPu, pPi, pL0, pL1, pH);

    // ---- bucketed CSR build ----
    hipMemsetAsync(bCntU, 0, 512 * sizeof(int), stream);   // bCntU + bCntI contiguous
    bhist_kernel<<<2 * ebs, 256, 0, stream>>>(iu_dst, bCntU, ui_dst, bCntI, E, ebs);
    bscan_kernel<<<1, 512, 0, stream>>>(bCntU, nbkU, bBaseU, bCurU, rowU + N_U,
                                        bCntI, nbkI, bBaseI, bCurI, rowI + N_I, E);
    bscatter_kernel<<<2 * ebs, 256, 0, stream>>>(iu_src, iu_dst, bCurU, pairsU,
                                                 ui_src, ui_dst, bCurI, pairsI, E, ebs);
    bfill_kernel<<<nbkU + nbkI, 256, 0, stream>>>(bBaseU, rowU, listsU, pairsU, N_U,
                                                  bBaseI, rowI, listsI, pairsI, N_I, nbkU);

    // ---- input projections (+bias, relu) -> bf16 h, one dispatch ----
    proj2_kernel<<<gU + gI, 256, 0, stream>>>(x_u, pPu, bp_u, hU, N_U, gU,
                                              x_i, pPi, bp_i, hI, N_I);

    for (int l = 0; l < L; ++l) {
        const ushort* pL = (l == 0) ? pL0 : pL1;
        // Y = h @ [Wl | Wr+I] -> bf16  (seg_mean(h)@Wl == seg_mean(h@Wl))
        gemm_layer2_kernel<<<gU + gI, 256, 0, stream>>>(hU, pL, Y_u, N_U, gU,
                                                        hI, Y_i, N_I);
        // fused gather-mean + residual(+I fold) + BN + relu; last U-layer also
        // writes fp32 out1 from the fp32 accumulator
        float* o1 = (l == L - 1) ? out1 : nullptr;
        gather2_kernel<<<aU + aI, 256, 0, stream>>>(
            Y_i, Y_u, hU, o1, rowU, listsU,
            bl + l * H, gamma + l * H, beta + l * H, mean + l * H, var + l * H,
            N_U, aU,
            Y_u, Y_i, hI, rowI, listsI, N_I);
    }

    // ---- head: out0 = hU(bf16) @ Wh + bh ----
    head_kernel<<<gU, 256, 0, stream>>>(hU, pH, bh, out, N_U);
}